// Round 11
// baseline (954.421 us; speedup 1.0000x reference)
//
#include <hip/hip_runtime.h>
#include <cstdint>
#include <cstddef>

using u16 = unsigned short;
using u32 = unsigned int;

typedef __attribute__((ext_vector_type(8))) short bf16x8;
typedef __attribute__((ext_vector_type(4))) float f32x4;

__device__ __forceinline__ u16 f2bf(float f) {
  union { float f; u32 u; } v; v.f = f;
  u32 r = v.u + 0x7FFFu + ((v.u >> 16) & 1u);
  return (u16)(r >> 16);
}
__device__ __forceinline__ float bf2f(u16 h) {
  union { u32 u; float f; } v; v.u = ((u32)h) << 16;
  return v.f;
}

__device__ __forceinline__ void gl_lds16(const void* g, void* l) {
  __builtin_amdgcn_global_load_lds(
      (const __attribute__((address_space(1))) void*)g,
      (__attribute__((address_space(3))) void*)l, 16, 0, 0);
}

// ---------------- fp32 -> bf16 weight convert, all 4 weights fused -------
__global__ __launch_bounds__(256) void k_f2bf4(
    const float* __restrict__ a0, const float* __restrict__ a1,
    const float* __restrict__ a2, const float* __restrict__ a3,
    u16* __restrict__ d0, u16* __restrict__ d1, u16* __restrict__ d2,
    u16* __restrict__ d3) {
  int i = blockIdx.x * 256 + threadIdx.x;
  if (i < 442368) d0[i] = f2bf(a0[i]);
  else if (i < 589824) d1[i - 442368] = f2bf(a1[i - 442368]);
  else if (i < 1179648) d2[i - 589824] = f2bf(a2[i - 589824]);
  else if (i < 1769472) d3[i - 1179648] = f2bf(a3[i - 1179648]);
}

// ---------------- combined rel-bias + shift-mask + pad tables ------------
// tbl[((h*4+wt))*4096 + j*64 + i]; wt = 2*(wh==7) + (ww==7); j>=49 -> -3e38
__global__ __launch_bounds__(256) void k_tbl(const float* __restrict__ relt,
                                             float* __restrict__ tbl) {
  int id = blockIdx.x * 256 + threadIdx.x;
  if (id >= 196608) return;
  int i = id & 63, j = (id >> 6) & 63;
  int wt = (id >> 12) & 3, h = id >> 14;
  float v;
  if (j >= 49) {
    v = -3e38f;
  } else {
    int ii = i < 49 ? i : 48;
    int r1 = ii / 7, c1 = ii % 7, r2 = j / 7, c2 = j % 7;
    v = relt[((r1 - r2 + 6) * 13 + (c1 - c2 + 6)) * 12 + h];
    int rr1 = (wt & 2) ? (r1 < 4 ? 1 : 2) : 0;
    int rr2 = (wt & 2) ? (r2 < 4 ? 1 : 2) : 0;
    int cc1 = (wt & 1) ? (c1 < 4 ? 1 : 2) : 0;
    int cc2 = (wt & 1) ? (c2 < 4 ? 1 : 2) : 0;
    if (rr1 != rr2 || cc1 != cc2) v -= 100.f;
  }
  tbl[id] = v;
}

// ---------------- LayerNorm (optionally fused shift+window gather) -------
template <int GATHER>
__global__ __launch_bounds__(256) void k_ln(const float* __restrict__ x,
                                            const float* __restrict__ g,
                                            const float* __restrict__ b,
                                            u16* __restrict__ out) {
  int wave = threadIdx.x >> 6, lane = threadIdx.x & 63;
  int idx = blockIdx.x * 4 + wave;  // output token index
  int src;
  if (GATHER) {
    int n = idx / 49, l = idx % 49;
    int bb = n >> 6, wi = n & 63;
    int wh = wi >> 3, ww = wi & 7;
    int r = l / 7, c = l % 7;
    int sr = wh * 7 + r + 3; if (sr >= 56) sr -= 56;
    int sc = ww * 7 + c + 3; if (sc >= 56) sc -= 56;
    src = bb * 3136 + sr * 56 + sc;
  } else {
    src = idx;
  }
  const float* xi = x + (size_t)src * 384;
  float2 v[3];
  float s = 0.f, sq = 0.f;
#pragma unroll
  for (int p = 0; p < 3; ++p) {
    v[p] = *(const float2*)(xi + p * 128 + lane * 2);
    s += v[p].x + v[p].y;
    sq += v[p].x * v[p].x + v[p].y * v[p].y;
  }
#pragma unroll
  for (int o = 32; o; o >>= 1) {
    s += __shfl_xor(s, o);
    sq += __shfl_xor(sq, o);
  }
  float mu = s * (1.f / 384.f);
  float var = sq * (1.f / 384.f) - mu * mu;
  float rstd = rsqrtf(var + 1e-5f);
  u16* oo = out + (size_t)idx * 384;
#pragma unroll
  for (int p = 0; p < 3; ++p) {
    int e = p * 128 + lane * 2;
    u16 o0 = f2bf((v[p].x - mu) * rstd * g[e] + b[e]);
    u16 o1 = f2bf((v[p].y - mu) * rstd * g[e + 1] + b[e + 1]);
    u32 pk = (u32)o0 | ((u32)o1 << 16);
    *(u32*)(oo + e) = pk;
  }
}

// ---------------- GEMM (R8-proven): 256x128 tile, 8 waves, single-buffer --
// stage -> __syncthreads -> compute -> __syncthreads. T2 XOR-swizzle
// both-sides -> 0 bank conflicts. XCD chunk swizzle (n-inner) for A L2 reuse.
// EPI_QKV: q/k -> qk buf (ldc=768, q pre-scaled); v -> vT[(win*384+d)*64+l]
// (vT is a DISJOINT region after the qk buffer -- R10 bug was overlap).
enum { EPI_QKV = 0, EPI_PROJ = 1, EPI_GELU = 2, EPI_FC2 = 3 };

template <int EPI>
__global__ __launch_bounds__(512, 2) void k_gemm3(
    const u16* __restrict__ A, const u16* __restrict__ Bw,
    const float* __restrict__ bias, u16* __restrict__ obf,
    float* __restrict__ of32, const float* __restrict__ addsrc,
    u16* __restrict__ vtout, int K, int lda, int ldb, int ldc, int NT) {
  __shared__ u16 As[256 * 64];  // 32 KB
  __shared__ u16 Bs[128 * 64];  // 16 KB
  // bijective XCD chunk swizzle (m204), n-inner for A-panel L2 reuse
  const int nwg = gridDim.x;
  const int q = nwg >> 3, r = nwg & 7;
  const int xcd = blockIdx.x & 7, rank = blockIdx.x >> 3;
  const int swz = (xcd < r ? xcd * (q + 1) : r * (q + 1) + (xcd - r) * q) + rank;
  const int m0 = (swz / NT) * 256, n0 = (swz % NT) * 128;

  const int tid = threadIdx.x;
  const int wid = tid >> 6, lane = tid & 63;
  const int wr = wid >> 1, wc = wid & 1;  // 4M x 2N waves, per-wave 64x64

  // staging: pre-swizzled global source; linear LDS dest (HW adds lane*16B)
  const int srow = tid >> 3;                      // 0..63
  const int scol = 8 * ((tid & 7) ^ (srow & 7));  // inverse-swizzled col
  const size_t abase = (size_t)(m0 + srow) * lda + scol;
  const size_t bbase = (size_t)(n0 + srow) * ldb + scol;
  const int dbase = wid * 512;  // (wid*8 rows)*64 u16

  f32x4 acc[4][4] = {};
  const int lrow = lane & 15;
  const int g8 = (lane >> 4) * 8;
  const int rx = (lrow & 7) << 3;  // read-side XOR (u16 units)

  const int NTK = K >> 6;

  for (int t = 0; t < NTK; ++t) {
    const int k0 = t << 6;
#pragma unroll
    for (int i = 0; i < 4; ++i)
      gl_lds16(A + abase + (size_t)(i * 64) * lda + k0,
               As + i * 4096 + dbase);
#pragma unroll
    for (int i = 0; i < 2; ++i)
      gl_lds16(Bw + bbase + (size_t)(i * 64) * ldb + k0,
               Bs + i * 4096 + dbase);
    __syncthreads();  // drains vmcnt/lgkm + barrier
    __builtin_amdgcn_s_setprio(1);
#pragma unroll
    for (int kk = 0; kk < 64; kk += 32) {
      bf16x8 af[4], bf[4];
#pragma unroll
      for (int mi = 0; mi < 4; ++mi) {
        int row = wr * 64 + mi * 16 + lrow;
        af[mi] = *(const bf16x8*)(&As[row * 64 + ((kk + g8) ^ rx)]);
      }
#pragma unroll
      for (int ni = 0; ni < 4; ++ni) {
        int row = wc * 64 + ni * 16 + lrow;
        bf[ni] = *(const bf16x8*)(&Bs[row * 64 + ((kk + g8) ^ rx)]);
      }
#pragma unroll
      for (int mi = 0; mi < 4; ++mi)
#pragma unroll
        for (int ni = 0; ni < 4; ++ni)
          acc[mi][ni] = __builtin_amdgcn_mfma_f32_16x16x32_bf16(
              af[mi], bf[ni], acc[mi][ni], 0, 0, 0);
    }
    __builtin_amdgcn_s_setprio(0);
    __syncthreads();  // protect buffers before next stage
  }

  // epilogue: D mapping col=lane&15, row=(lane>>4)*4+reg
  const int erow = (lane >> 4) * 4;
  const int ecol = lane & 15;
#pragma unroll
  for (int mi = 0; mi < 4; ++mi) {
#pragma unroll
    for (int ni = 0; ni < 4; ++ni) {
      int gcol = n0 + wc * 64 + ni * 16 + ecol;
      float bv = bias[gcol];
#pragma unroll
      for (int r4 = 0; r4 < 4; ++r4) {
        int grow = m0 + wr * 64 + mi * 16 + erow + r4;
        float v = acc[mi][ni][r4] + bv;
        if (EPI == EPI_QKV) {
          if (gcol < 768) {
            // fold attention scale 1/sqrt(32) into q columns (cols < 384)
            float vv = (gcol < 384) ? v * 0.17677669529663689f : v;
            obf[(size_t)grow * ldc + gcol] = f2bf(vv);
          } else {
            // v -> transposed layout vT[(win*384 + d)*64 + l]
            int nwin = grow / 49, l = grow - nwin * 49;
            vtout[((size_t)nwin * 384 + (gcol - 768)) * 64 + l] = f2bf(v);
          }
        } else if (EPI == EPI_GELU) {
          float gl = 0.5f * v * (1.f + erff(v * 0.70710678118f));
          obf[(size_t)grow * ldc + gcol] = f2bf(gl);
        } else if (EPI == EPI_PROJ) {
          int nwin = grow / 49, l = grow % 49;
          int bb = nwin >> 6, wi = nwin & 63;
          int wh = wi >> 3, ww = wi & 7;
          int rr = l / 7, cc = l % 7;
          int sr = wh * 7 + rr + 3; if (sr >= 56) sr -= 56;
          int sc = ww * 7 + cc + 3; if (sc >= 56) sc -= 56;
          size_t idx = ((size_t)(bb * 3136 + sr * 56 + sc)) * 384 + gcol;
          of32[idx] = addsrc[idx] + v;
        } else {  // EPI_FC2: accumulate into (row-chunked) d_out
          size_t idx = (size_t)grow * 384 + gcol;
          of32[idx] = of32[idx] + v;
        }
      }
    }
  }
}

// ---------------- MFMA windowed attention v3 ------------------------------
// Q/K fragments from qk buffer (row stride 768); V fragments from transposed
// vT (coalesced 16B/lane). Table C-init (bias+mask+pad); lane-local softmax;
// P via wave-private swizzled LDS. j>=49: tbl=-3e38 -> P=0 annihilates the
// finite garbage in vT's padding columns.
__global__ __launch_bounds__(64) void k_attn3(const u16* __restrict__ qk,
                                              const u16* __restrict__ vt,
                                              const float* __restrict__ tbl,
                                              u16* __restrict__ out) {
  __shared__ u16 P[64 * 64];  // 8KB, wave-private
  const int bx = blockIdx.x;
  const int n = bx / 12, h = bx - n * 12;
  const int lane = threadIdx.x & 63;
  const int g = lane >> 4, c = lane & 15;
  const u16* base = qk + (size_t)n * 49 * 768 + h * 32;
  const int wi = n & 63;
  const int wt = (((wi >> 3) == 7) ? 2 : 0) | (((wi & 7) == 7) ? 1 : 0);
  const float* T = tbl + (size_t)((h << 2) | wt) * 4096;

  f32x4 st[4][4];  // [kj][qi]; reg r -> j = kj*16+g*4+r, i = qi*16+c
#pragma unroll
  for (int kj = 0; kj < 4; ++kj)
#pragma unroll
    for (int qi = 0; qi < 4; ++qi)
#pragma unroll
      for (int r = 0; r < 4; ++r)
        st[kj][qi][r] = T[(kj * 16 + g * 4 + r) * 64 + qi * 16 + c];

  bf16x8 qf[4], kf[4];
#pragma unroll
  for (int t = 0; t < 4; ++t) {
    int row = t * 16 + c; if (row > 48) row = 48;
    qf[t] = *(const bf16x8*)(base + (size_t)row * 768 + g * 8);
    kf[t] = *(const bf16x8*)(base + (size_t)row * 768 + 384 + g * 8);
  }

#pragma unroll
  for (int kj = 0; kj < 4; ++kj)
#pragma unroll
    for (int qi = 0; qi < 4; ++qi)
      st[kj][qi] = __builtin_amdgcn_mfma_f32_16x16x32_bf16(kf[kj], qf[qi],
                                                           st[kj][qi], 0, 0, 0);

#pragma unroll
  for (int qi = 0; qi < 4; ++qi) {
    float m = -3e38f;
#pragma unroll
    for (int kj = 0; kj < 4; ++kj)
#pragma unroll
      for (int r = 0; r < 4; ++r) m = fmaxf(m, st[kj][qi][r]);
    m = fmaxf(m, __shfl_xor(m, 16));
    m = fmaxf(m, __shfl_xor(m, 32));
    float sum = 0.f;
#pragma unroll
    for (int kj = 0; kj < 4; ++kj)
#pragma unroll
      for (int r = 0; r < 4; ++r) {
        float e = __expf(st[kj][qi][r] - m);
        st[kj][qi][r] = e;
        sum += e;
      }
    sum += __shfl_xor(sum, 16);
    sum += __shfl_xor(sum, 32);
    float inv = 1.f / sum;
    int i = qi * 16 + c;
#pragma unroll
    for (int kj = 0; kj < 4; ++kj)
#pragma unroll
      for (int hh = 0; hh < 2; ++hh) {
        u32 pk = (u32)f2bf(st[kj][qi][2 * hh] * inv) |
                 ((u32)f2bf(st[kj][qi][2 * hh + 1] * inv) << 16);
        int idx = (i * 64 + kj * 16 + g * 4 + 2 * hh) ^ ((i & 7) << 3);
        *(u32*)(P + idx) = pk;
      }
  }

  // PV: A = P rows (LDS), B = vT rows (coalesced bf16x8 global loads)
  const u16* vbase = vt + ((size_t)n * 384 + h * 32) * 64;
  f32x4 o[4][2] = {};
#pragma unroll
  for (int k0 = 0; k0 < 2; ++k0) {
    bf16x8 pa[4], vb[2];
#pragma unroll
    for (int qi = 0; qi < 4; ++qi) {
      int qq = qi * 16 + c;
      pa[qi] = *(const bf16x8*)(P + ((qq * 64 + k0 * 32 + g * 8) ^ ((qq & 7) << 3)));
    }
#pragma unroll
    for (int ni = 0; ni < 2; ++ni)
      vb[ni] = *(const bf16x8*)(vbase + (size_t)(ni * 16 + c) * 64 + k0 * 32 +
                                g * 8);
#pragma unroll
    for (int ni = 0; ni < 2; ++ni)
#pragma unroll
      for (int qi = 0; qi < 4; ++qi)
        o[qi][ni] = __builtin_amdgcn_mfma_f32_16x16x32_bf16(pa[qi], vb[ni],
                                                            o[qi][ni], 0, 0, 0);
  }

  u16* ob = out + (size_t)n * 18816 + h * 32;
#pragma unroll
  for (int qi = 0; qi < 4; ++qi)
#pragma unroll
    for (int r = 0; r < 4; ++r) {
      int qq = qi * 16 + g * 4 + r;
      if (qq < 49) {
#pragma unroll
        for (int ni = 0; ni < 2; ++ni)
          ob[(size_t)qq * 384 + ni * 16 + c] = f2bf(o[qi][ni][r]);
      }
    }
}

// --------------------------------------------------------------------------
extern "C" void kernel_launch(void* const* d_in, const int* in_sizes, int n_in,
                              void* d_out, int out_size, void* d_ws,
                              size_t ws_size, hipStream_t stream) {
  const float* hidden = (const float*)d_in[0];
  const float* ln1g = (const float*)d_in[1];
  const float* ln1b = (const float*)d_in[2];
  const float* qkvw = (const float*)d_in[3];
  const float* qkvb = (const float*)d_in[4];
  const float* outw = (const float*)d_in[5];
  const float* outb = (const float*)d_in[6];
  const float* relt = (const float*)d_in[7];
  const float* ln2g = (const float*)d_in[8];
  const float* ln2b = (const float*)d_in[9];
  const float* fc1w = (const float*)d_in[10];
  const float* fc1b = (const float*)d_in[11];
  const float* fc2w = (const float*)d_in[12];
  const float* fc2b = (const float*)d_in[13];
  float* out = (float*)d_out;

  // ws layout (u16 units). Peak 167.7M u16 = 335.4 MB.
  u16* wq = (u16*)d_ws;            // 1152*384 (dead after qkv GEMM -> tbl)
  u16* wo = wq + 442368;           // 384*384
  u16* w1 = wo + 147456;           // 1536*384
  u16* w2 = w1 + 589824;           // 384*1536
  u16* xw = w2 + 589824;           // 100352*384 (LN1 out, then attn_out)
  u16* qk = xw + 38535168;         // 100352*768 q/k (live qkvGEMM->attn)
  u16* vT = qk + 77070336;         // 2048*384*64 (live qkvGEMM->attn)
  u16* xn = qk;                    // LN2 out reuses qk (dead after attn)
  u16* hbuf = qk + 38535168;       // 50176*1536 = qk tail + vT (both dead)
  float* tbl = (float*)wq;         // 196608 f32 <= wq region (221184 f32)

  // all 4 weight converts in one launch
  k_f2bf4<<<6912, 256, 0, stream>>>(qkvw, outw, fc1w, fc2w, wq, wo, w1, w2);

  // LN1 + shift + window partition
  k_ln<1><<<25088, 256, 0, stream>>>(hidden, ln1g, ln1b, xw);

  // qkv GEMM: q/k -> qk (ldc=768, q pre-scaled); v -> vT transposed
  k_gemm3<EPI_QKV><<<392 * 9, 512, 0, stream>>>(
      xw, wq, qkvb, qk, nullptr, nullptr, vT, 384, 384, 384, 768, 9);

  // bias+mask tables into the now-dead wq region
  k_tbl<<<768, 256, 0, stream>>>(relt, tbl);

  // MFMA attention (reads qk + vT; writes attn_out into xw buffer)
  k_attn3<<<24576, 64, 0, stream>>>(qk, vT, tbl, xw);

  // out proj + window reverse + unshift + residual -> d_out (= x)
  k_gemm3<EPI_PROJ><<<392 * 3, 512, 0, stream>>>(
      xw, wo, outb, nullptr, out, hidden, nullptr, 384, 384, 384, 384, 3);

  // LN2
  k_ln<0><<<25088, 256, 0, stream>>>(out, ln2g, ln2b, xn);

  // MLP, M-chunked (two row-halves), full N=1536 / K=1536
  for (int ch = 0; ch < 2; ++ch) {
    const u16* xa = xn + (size_t)ch * 50176 * 384;
    float* oc = out + (size_t)ch * 50176 * 384;
    k_gemm3<EPI_GELU><<<196 * 12, 512, 0, stream>>>(
        xa, w1, fc1b, hbuf, nullptr, nullptr, nullptr, 384, 384, 384, 1536, 12);
    k_gemm3<EPI_FC2><<<196 * 3, 512, 0, stream>>>(
        hbuf, w2, fc2b, nullptr, oc, nullptr, nullptr, 1536, 1536, 1536, 384, 3);
  }
}

// Round 12
// 924.906 us; speedup vs baseline: 1.0319x; 1.0319x over previous
//
#include <hip/hip_runtime.h>
#include <cstdint>
#include <cstddef>

using u16 = unsigned short;
using u32 = unsigned int;

typedef __attribute__((ext_vector_type(8))) short bf16x8;
typedef __attribute__((ext_vector_type(4))) float f32x4;

__device__ __forceinline__ u16 f2bf(float f) {
  union { float f; u32 u; } v; v.f = f;
  u32 r = v.u + 0x7FFFu + ((v.u >> 16) & 1u);
  return (u16)(r >> 16);
}
__device__ __forceinline__ float bf2f(u16 h) {
  union { u32 u; float f; } v; v.u = ((u32)h) << 16;
  return v.f;
}

__device__ __forceinline__ void gl_lds16(const void* g, void* l) {
  __builtin_amdgcn_global_load_lds(
      (const __attribute__((address_space(1))) void*)g,
      (__attribute__((address_space(3))) void*)l, 16, 0, 0);
}

// ---------------- fp32 -> bf16 weight convert, all 4 weights fused -------
__global__ __launch_bounds__(256) void k_f2bf4(
    const float* __restrict__ a0, const float* __restrict__ a1,
    const float* __restrict__ a2, const float* __restrict__ a3,
    u16* __restrict__ d0, u16* __restrict__ d1, u16* __restrict__ d2,
    u16* __restrict__ d3) {
  int i = blockIdx.x * 256 + threadIdx.x;
  if (i < 442368) d0[i] = f2bf(a0[i]);
  else if (i < 589824) d1[i - 442368] = f2bf(a1[i - 442368]);
  else if (i < 1179648) d2[i - 589824] = f2bf(a2[i - 589824]);
  else if (i < 1769472) d3[i - 1179648] = f2bf(a3[i - 1179648]);
}

// ---------------- combined rel-bias + shift-mask + pad tables ------------
// tbl[((h*4+wt))*4096 + j*64 + i]; wt = 2*(wh==7) + (ww==7); j>=49 -> -3e38
__global__ __launch_bounds__(256) void k_tbl(const float* __restrict__ relt,
                                             float* __restrict__ tbl) {
  int id = blockIdx.x * 256 + threadIdx.x;
  if (id >= 196608) return;
  int i = id & 63, j = (id >> 6) & 63;
  int wt = (id >> 12) & 3, h = id >> 14;
  float v;
  if (j >= 49) {
    v = -3e38f;
  } else {
    int ii = i < 49 ? i : 48;
    int r1 = ii / 7, c1 = ii % 7, r2 = j / 7, c2 = j % 7;
    v = relt[((r1 - r2 + 6) * 13 + (c1 - c2 + 6)) * 12 + h];
    int rr1 = (wt & 2) ? (r1 < 4 ? 1 : 2) : 0;
    int rr2 = (wt & 2) ? (r2 < 4 ? 1 : 2) : 0;
    int cc1 = (wt & 1) ? (c1 < 4 ? 1 : 2) : 0;
    int cc2 = (wt & 1) ? (c2 < 4 ? 1 : 2) : 0;
    if (rr1 != rr2 || cc1 != cc2) v -= 100.f;
  }
  tbl[id] = v;
}

// ---------------- LayerNorm (optionally fused shift+window gather) -------
template <int GATHER>
__global__ __launch_bounds__(256) void k_ln(const float* __restrict__ x,
                                            const float* __restrict__ g,
                                            const float* __restrict__ b,
                                            u16* __restrict__ out) {
  int wave = threadIdx.x >> 6, lane = threadIdx.x & 63;
  int idx = blockIdx.x * 4 + wave;  // output token index
  int src;
  if (GATHER) {
    int n = idx / 49, l = idx % 49;
    int bb = n >> 6, wi = n & 63;
    int wh = wi >> 3, ww = wi & 7;
    int r = l / 7, c = l % 7;
    int sr = wh * 7 + r + 3; if (sr >= 56) sr -= 56;
    int sc = ww * 7 + c + 3; if (sc >= 56) sc -= 56;
    src = bb * 3136 + sr * 56 + sc;
  } else {
    src = idx;
  }
  const float* xi = x + (size_t)src * 384;
  float2 v[3];
  float s = 0.f, sq = 0.f;
#pragma unroll
  for (int p = 0; p < 3; ++p) {
    v[p] = *(const float2*)(xi + p * 128 + lane * 2);
    s += v[p].x + v[p].y;
    sq += v[p].x * v[p].x + v[p].y * v[p].y;
  }
#pragma unroll
  for (int o = 32; o; o >>= 1) {
    s += __shfl_xor(s, o);
    sq += __shfl_xor(sq, o);
  }
  float mu = s * (1.f / 384.f);
  float var = sq * (1.f / 384.f) - mu * mu;
  float rstd = rsqrtf(var + 1e-5f);
  u16* oo = out + (size_t)idx * 384;
#pragma unroll
  for (int p = 0; p < 3; ++p) {
    int e = p * 128 + lane * 2;
    u16 o0 = f2bf((v[p].x - mu) * rstd * g[e] + b[e]);
    u16 o1 = f2bf((v[p].y - mu) * rstd * g[e + 1] + b[e + 1]);
    u32 pk = (u32)o0 | ((u32)o1 << 16);
    *(u32*)(oo + e) = pk;
  }
}

// ---------------- GEMM v6: 256x128 tile, 4 waves of 128x64, single-buffer -
// R8 loop semantics (stage -> __syncthreads -> compute -> __syncthreads),
// but per-wave output doubled to 128x64 (2Mx2N waves): LDS fragment reads
// drop from 0.5 to 0.375 per MFMA -> LDS-BW ceiling rises 46%->57%.
// 48KB LDS + ~196 VGPR -> 2 blocks/CU co-resident hide the sync drain.
// T2 XOR-swizzle both-sides -> 0 bank conflicts. XCD chunk swizzle (n-inner).
enum { EPI_QKV = 0, EPI_PROJ = 1, EPI_GELU = 2, EPI_FC2 = 3 };

template <int EPI>
__global__ __launch_bounds__(256, 2) void k_gemm6(
    const u16* __restrict__ A, const u16* __restrict__ Bw,
    const float* __restrict__ bias, u16* __restrict__ obf,
    float* __restrict__ of32, const float* __restrict__ addsrc,
    int K, int lda, int ldb, int ldc, int NT) {
  __shared__ u16 As[256 * 64];  // 32 KB
  __shared__ u16 Bs[128 * 64];  // 16 KB
  // bijective XCD chunk swizzle (m204), n-inner for A-panel L2 reuse
  const int nwg = gridDim.x;
  const int q = nwg >> 3, r = nwg & 7;
  const int xcd = blockIdx.x & 7, rank = blockIdx.x >> 3;
  const int swz = (xcd < r ? xcd * (q + 1) : r * (q + 1) + (xcd - r) * q) + rank;
  const int m0 = (swz / NT) * 256, n0 = (swz % NT) * 128;

  const int tid = threadIdx.x;
  const int wid = tid >> 6, lane = tid & 63;
  const int wr = wid >> 1, wc = wid & 1;  // 2M x 2N waves, per-wave 128x64

  // staging: pre-swizzled global source; linear LDS dest (HW adds lane*16B).
  // 256 threads cover 32 rows x 64 cols per issue.
  const int srow = tid >> 3;                      // 0..31
  const int scol = 8 * ((tid & 7) ^ (srow & 7));  // inverse-swizzled col
  const size_t abase = (size_t)(m0 + srow) * lda + scol;
  const size_t bbase = (size_t)(n0 + srow) * ldb + scol;
  const int dbase = wid * 512;  // per-wave dest chunk within a 2048-u16 slab

  f32x4 acc[8][4] = {};
  const int lrow = lane & 15;
  const int g8 = (lane >> 4) * 8;
  const int rx = (lrow & 7) << 3;  // read-side XOR (u16 units)

  const int NTK = K >> 6;

  for (int t = 0; t < NTK; ++t) {
    const int k0 = t << 6;
    // stage A (8 x 32-row slabs) + B (4 slabs)
#pragma unroll
    for (int i = 0; i < 8; ++i)
      gl_lds16(A + abase + (size_t)(i * 32) * lda + k0,
               As + i * 2048 + dbase);
#pragma unroll
    for (int i = 0; i < 4; ++i)
      gl_lds16(Bw + bbase + (size_t)(i * 32) * ldb + k0,
               Bs + i * 2048 + dbase);
    __syncthreads();  // drains vmcnt/lgkm + barrier (R8-proven semantics)
    __builtin_amdgcn_s_setprio(1);
#pragma unroll
    for (int kk = 0; kk < 64; kk += 32) {
      bf16x8 af[8], bf[4];
#pragma unroll
      for (int mi = 0; mi < 8; ++mi) {
        int row = wr * 128 + mi * 16 + lrow;
        af[mi] = *(const bf16x8*)(&As[row * 64 + ((kk + g8) ^ rx)]);
      }
#pragma unroll
      for (int ni = 0; ni < 4; ++ni) {
        int row = wc * 64 + ni * 16 + lrow;
        bf[ni] = *(const bf16x8*)(&Bs[row * 64 + ((kk + g8) ^ rx)]);
      }
#pragma unroll
      for (int mi = 0; mi < 8; ++mi)
#pragma unroll
        for (int ni = 0; ni < 4; ++ni)
          acc[mi][ni] = __builtin_amdgcn_mfma_f32_16x16x32_bf16(
              af[mi], bf[ni], acc[mi][ni], 0, 0, 0);
    }
    __builtin_amdgcn_s_setprio(0);
    __syncthreads();  // protect buffers before next stage
  }

  // epilogue: D mapping col=lane&15, row=(lane>>4)*4+reg
  const int erow = (lane >> 4) * 4;
  const int ecol = lane & 15;
#pragma unroll
  for (int mi = 0; mi < 8; ++mi) {
#pragma unroll
    for (int ni = 0; ni < 4; ++ni) {
      int gcol = n0 + wc * 64 + ni * 16 + ecol;
      float bv = bias[gcol];
#pragma unroll
      for (int r4 = 0; r4 < 4; ++r4) {
        int grow = m0 + wr * 128 + mi * 16 + erow + r4;
        float v = acc[mi][ni][r4] + bv;
        if (EPI == EPI_QKV) {
          // fold attention scale 1/sqrt(32) into q columns (cols < 384)
          float vv = (gcol < 384) ? v * 0.17677669529663689f : v;
          obf[(size_t)grow * ldc + gcol] = f2bf(vv);
        } else if (EPI == EPI_GELU) {
          float gl = 0.5f * v * (1.f + erff(v * 0.70710678118f));
          obf[(size_t)grow * ldc + gcol] = f2bf(gl);
        } else if (EPI == EPI_PROJ) {
          int nwin = grow / 49, l = grow % 49;
          int bb = nwin >> 6, wi = nwin & 63;
          int wh = wi >> 3, ww = wi & 7;
          int rr = l / 7, cc = l % 7;
          int sr = wh * 7 + rr + 3; if (sr >= 56) sr -= 56;
          int sc = ww * 7 + cc + 3; if (sc >= 56) sc -= 56;
          size_t idx = ((size_t)(bb * 3136 + sr * 56 + sc)) * 384 + gcol;
          of32[idx] = addsrc[idx] + v;
        } else {  // EPI_FC2: accumulate into (row-chunked) d_out
          size_t idx = (size_t)grow * 384 + gcol;
          of32[idx] = of32[idx] + v;
        }
      }
    }
  }
}

// ---------------- MFMA windowed attention v2 (R8-proven) ------------------
__global__ __launch_bounds__(64) void k_attn2(const u16* __restrict__ qkv,
                                              const float* __restrict__ tbl,
                                              u16* __restrict__ out) {
  __shared__ u16 P[64 * 64];  // 8KB, wave-private
  const int bx = blockIdx.x;
  const int n = bx / 12, h = bx - n * 12;
  const int lane = threadIdx.x & 63;
  const int g = lane >> 4, c = lane & 15;
  const u16* base = qkv + (size_t)n * 56448 + h * 32;
  const int wi = n & 63;
  const int wt = (((wi >> 3) == 7) ? 2 : 0) | (((wi & 7) == 7) ? 1 : 0);
  const float* T = tbl + (size_t)((h << 2) | wt) * 4096;

  f32x4 st[4][4];  // [kj][qi]; reg r -> j = kj*16+g*4+r, i = qi*16+c
#pragma unroll
  for (int kj = 0; kj < 4; ++kj)
#pragma unroll
    for (int qi = 0; qi < 4; ++qi)
#pragma unroll
      for (int r = 0; r < 4; ++r)
        st[kj][qi][r] = T[(kj * 16 + g * 4 + r) * 64 + qi * 16 + c];

  bf16x8 qf[4], kf[4];
#pragma unroll
  for (int t = 0; t < 4; ++t) {
    int row = t * 16 + c; if (row > 48) row = 48;
    qf[t] = *(const bf16x8*)(base + (size_t)row * 1152 + g * 8);
    kf[t] = *(const bf16x8*)(base + (size_t)row * 1152 + 384 + g * 8);
  }

#pragma unroll
  for (int kj = 0; kj < 4; ++kj)
#pragma unroll
    for (int qi = 0; qi < 4; ++qi)
      st[kj][qi] = __builtin_amdgcn_mfma_f32_16x16x32_bf16(kf[kj], qf[qi],
                                                           st[kj][qi], 0, 0, 0);

#pragma unroll
  for (int qi = 0; qi < 4; ++qi) {
    float m = -3e38f;
#pragma unroll
    for (int kj = 0; kj < 4; ++kj)
#pragma unroll
      for (int r = 0; r < 4; ++r) m = fmaxf(m, st[kj][qi][r]);
    m = fmaxf(m, __shfl_xor(m, 16));
    m = fmaxf(m, __shfl_xor(m, 32));
    float sum = 0.f;
#pragma unroll
    for (int kj = 0; kj < 4; ++kj)
#pragma unroll
      for (int r = 0; r < 4; ++r) {
        float e = __expf(st[kj][qi][r] - m);
        st[kj][qi][r] = e;
        sum += e;
      }
    sum += __shfl_xor(sum, 16);
    sum += __shfl_xor(sum, 32);
    float inv = 1.f / sum;
    int i = qi * 16 + c;
#pragma unroll
    for (int kj = 0; kj < 4; ++kj)
#pragma unroll
      for (int hh = 0; hh < 2; ++hh) {
        u32 pk = (u32)f2bf(st[kj][qi][2 * hh] * inv) |
                 ((u32)f2bf(st[kj][qi][2 * hh + 1] * inv) << 16);
        int idx = (i * 64 + kj * 16 + g * 4 + 2 * hh) ^ ((i & 7) << 3);
        *(u32*)(P + idx) = pk;
      }
  }

  f32x4 o[4][2] = {};
#pragma unroll
  for (int k0 = 0; k0 < 2; ++k0) {
    bf16x8 pa[4], vb[2];
#pragma unroll
    for (int qi = 0; qi < 4; ++qi) {
      int qq = qi * 16 + c;
      pa[qi] = *(const bf16x8*)(P + ((qq * 64 + k0 * 32 + g * 8) ^ ((qq & 7) << 3)));
    }
#pragma unroll
    for (int ni = 0; ni < 2; ++ni) {
      union { bf16x8 v; u16 a[8]; } vu;
#pragma unroll
      for (int e = 0; e < 8; ++e) {
        int j = k0 * 32 + g * 8 + e;
        int jr = j > 48 ? 48 : j;
        vu.a[e] = base[(size_t)jr * 1152 + 768 + ni * 16 + c];
      }
      vb[ni] = vu.v;
#pragma unroll
      for (int qi = 0; qi < 4; ++qi)
        o[qi][ni] = __builtin_amdgcn_mfma_f32_16x16x32_bf16(pa[qi], vb[ni],
                                                            o[qi][ni], 0, 0, 0);
    }
  }

  u16* ob = out + (size_t)n * 18816 + h * 32;
#pragma unroll
  for (int qi = 0; qi < 4; ++qi)
#pragma unroll
    for (int r = 0; r < 4; ++r) {
      int qq = qi * 16 + g * 4 + r;
      if (qq < 49) {
#pragma unroll
        for (int ni = 0; ni < 2; ++ni)
          ob[(size_t)qq * 384 + ni * 16 + c] = f2bf(o[qi][ni][r]);
      }
    }
}

// --------------------------------------------------------------------------
extern "C" void kernel_launch(void* const* d_in, const int* in_sizes, int n_in,
                              void* d_out, int out_size, void* d_ws,
                              size_t ws_size, hipStream_t stream) {
  const float* hidden = (const float*)d_in[0];
  const float* ln1g = (const float*)d_in[1];
  const float* ln1b = (const float*)d_in[2];
  const float* qkvw = (const float*)d_in[3];
  const float* qkvb = (const float*)d_in[4];
  const float* outw = (const float*)d_in[5];
  const float* outb = (const float*)d_in[6];
  const float* relt = (const float*)d_in[7];
  const float* ln2g = (const float*)d_in[8];
  const float* ln2b = (const float*)d_in[9];
  const float* fc1w = (const float*)d_in[10];
  const float* fc1b = (const float*)d_in[11];
  const float* fc2w = (const float*)d_in[12];
  const float* fc2b = (const float*)d_in[13];
  float* out = (float*)d_out;

  u16* wq = (u16*)d_ws;            // 1152*384 (dead after qkv GEMM -> tbl)
  u16* wo = wq + 442368;           // 384*384
  u16* w1 = wo + 147456;           // 1536*384
  u16* w2 = w1 + 589824;           // 384*1536
  u16* xw = w2 + 589824;           // 100352*384  (also attn_out)
  u16* qkv = xw + 38535168;        // 100352*1152 (region reused below)
  u16* xn = qkv;                   // 100352*384
  u16* hbuf = xn + 38535168;       // 50176*1536 (row-half MLP buffer)
  float* tbl = (float*)wq;         // 196608 f32 <= wq region (221184 f32)

  // all 4 weight converts in one launch
  k_f2bf4<<<6912, 256, 0, stream>>>(qkvw, outw, fc1w, fc2w, wq, wo, w1, w2);

  // LN1 + shift + window partition
  k_ln<1><<<25088, 256, 0, stream>>>(hidden, ln1g, ln1b, xw);

  // qkv = xw @ qkv_w^T + b  (q cols pre-scaled by 1/sqrt(32))
  k_gemm6<EPI_QKV><<<392 * 9, 256, 0, stream>>>(
      xw, wq, qkvb, qkv, nullptr, nullptr, 384, 384, 384, 1152, 9);

  // bias+mask tables into the now-dead wq region
  k_tbl<<<768, 256, 0, stream>>>(relt, tbl);

  // MFMA attention (writes attn_out into xw buffer)
  k_attn2<<<24576, 64, 0, stream>>>(qkv, tbl, xw);

  // out proj + window reverse + unshift + residual -> d_out (= x)
  k_gemm6<EPI_PROJ><<<392 * 3, 256, 0, stream>>>(
      xw, wo, outb, nullptr, out, hidden, 384, 384, 384, 384, 3);

  // LN2
  k_ln<0><<<25088, 256, 0, stream>>>(out, ln2g, ln2b, xn);

  // MLP, M-chunked (two row-halves), full N=1536 / K=1536
  for (int ch = 0; ch < 2; ++ch) {
    const u16* xa = xn + (size_t)ch * 50176 * 384;
    float* oc = out + (size_t)ch * 50176 * 384;
    k_gemm6<EPI_GELU><<<196 * 12, 256, 0, stream>>>(
        xa, w1, fc1b, hbuf, nullptr, nullptr, 384, 384, 384, 1536, 12);
    k_gemm6<EPI_FC2><<<196 * 3, 256, 0, stream>>>(
        hbuf, w2, fc2b, nullptr, oc, nullptr, 1536, 1536, 1536, 384, 3);
  }
}

// Round 13
// 907.496 us; speedup vs baseline: 1.0517x; 1.0192x over previous
//
#include <hip/hip_runtime.h>
#include <cstdint>
#include <cstddef>

using u16 = unsigned short;
using u32 = unsigned int;

typedef __attribute__((ext_vector_type(8))) short bf16x8;
typedef __attribute__((ext_vector_type(4))) float f32x4;

__device__ __forceinline__ u16 f2bf(float f) {
  union { float f; u32 u; } v; v.f = f;
  u32 r = v.u + 0x7FFFu + ((v.u >> 16) & 1u);
  return (u16)(r >> 16);
}
__device__ __forceinline__ float bf2f(u16 h) {
  union { u32 u; float f; } v; v.u = ((u32)h) << 16;
  return v.f;
}

__device__ __forceinline__ void gl_lds16(const void* g, void* l) {
  __builtin_amdgcn_global_load_lds(
      (const __attribute__((address_space(1))) void*)g,
      (__attribute__((address_space(3))) void*)l, 16, 0, 0);
}

// tanh-form GELU via exp (≈13 VALU ops vs ~25 for erff; |Δ| ≤ ~1e-3)
__device__ __forceinline__ float gelu_fast(float v) {
  float u = v * (0.7978845608f + 0.0356774081f * v * v);
  float e = __expf(-2.f * fabsf(u));
  float th = (1.f - e) / (1.f + e);
  th = (u >= 0.f) ? th : -th;
  return 0.5f * v * (1.f + th);
}

// ---------------- fp32 -> bf16 weight convert, all 4 weights fused -------
__global__ __launch_bounds__(256) void k_f2bf4(
    const float* __restrict__ a0, const float* __restrict__ a1,
    const float* __restrict__ a2, const float* __restrict__ a3,
    u16* __restrict__ d0, u16* __restrict__ d1, u16* __restrict__ d2,
    u16* __restrict__ d3) {
  int i = blockIdx.x * 256 + threadIdx.x;
  if (i < 442368) d0[i] = f2bf(a0[i]);
  else if (i < 589824) d1[i - 442368] = f2bf(a1[i - 442368]);
  else if (i < 1179648) d2[i - 589824] = f2bf(a2[i - 589824]);
  else if (i < 1769472) d3[i - 1179648] = f2bf(a3[i - 1179648]);
}

// ---------------- combined rel-bias + shift-mask + pad tables ------------
// tbl[((h*4+wt))*4096 + j*64 + i]; wt = 2*(wh==7) + (ww==7); j>=49 -> -3e38
__global__ __launch_bounds__(256) void k_tbl(const float* __restrict__ relt,
                                             float* __restrict__ tbl) {
  int id = blockIdx.x * 256 + threadIdx.x;
  if (id >= 196608) return;
  int i = id & 63, j = (id >> 6) & 63;
  int wt = (id >> 12) & 3, h = id >> 14;
  float v;
  if (j >= 49) {
    v = -3e38f;
  } else {
    int ii = i < 49 ? i : 48;
    int r1 = ii / 7, c1 = ii % 7, r2 = j / 7, c2 = j % 7;
    v = relt[((r1 - r2 + 6) * 13 + (c1 - c2 + 6)) * 12 + h];
    int rr1 = (wt & 2) ? (r1 < 4 ? 1 : 2) : 0;
    int rr2 = (wt & 2) ? (r2 < 4 ? 1 : 2) : 0;
    int cc1 = (wt & 1) ? (c1 < 4 ? 1 : 2) : 0;
    int cc2 = (wt & 1) ? (c2 < 4 ? 1 : 2) : 0;
    if (rr1 != rr2 || cc1 != cc2) v -= 100.f;
  }
  tbl[id] = v;
}

// ---------------- LayerNorm (optionally fused shift+window gather) -------
template <int GATHER>
__global__ __launch_bounds__(256) void k_ln(const float* __restrict__ x,
                                            const float* __restrict__ g,
                                            const float* __restrict__ b,
                                            u16* __restrict__ out) {
  int wave = threadIdx.x >> 6, lane = threadIdx.x & 63;
  int idx = blockIdx.x * 4 + wave;  // output token index
  int src;
  if (GATHER) {
    int n = idx / 49, l = idx % 49;
    int bb = n >> 6, wi = n & 63;
    int wh = wi >> 3, ww = wi & 7;
    int r = l / 7, c = l % 7;
    int sr = wh * 7 + r + 3; if (sr >= 56) sr -= 56;
    int sc = ww * 7 + c + 3; if (sc >= 56) sc -= 56;
    src = bb * 3136 + sr * 56 + sc;
  } else {
    src = idx;
  }
  const float* xi = x + (size_t)src * 384;
  float2 v[3];
  float s = 0.f, sq = 0.f;
#pragma unroll
  for (int p = 0; p < 3; ++p) {
    v[p] = *(const float2*)(xi + p * 128 + lane * 2);
    s += v[p].x + v[p].y;
    sq += v[p].x * v[p].x + v[p].y * v[p].y;
  }
#pragma unroll
  for (int o = 32; o; o >>= 1) {
    s += __shfl_xor(s, o);
    sq += __shfl_xor(sq, o);
  }
  float mu = s * (1.f / 384.f);
  float var = sq * (1.f / 384.f) - mu * mu;
  float rstd = rsqrtf(var + 1e-5f);
  u16* oo = out + (size_t)idx * 384;
#pragma unroll
  for (int p = 0; p < 3; ++p) {
    int e = p * 128 + lane * 2;
    u16 o0 = f2bf((v[p].x - mu) * rstd * g[e] + b[e]);
    u16 o1 = f2bf((v[p].y - mu) * rstd * g[e + 1] + b[e + 1]);
    u32 pk = (u32)o0 | ((u32)o1 << 16);
    *(u32*)(oo + e) = pk;
  }
}

// ---------------- GEMM (R8-proven): 256x128 tile, 8 waves, single-buffer --
// stage -> __syncthreads -> compute -> __syncthreads. T2 XOR-swizzle
// both-sides -> 0 bank conflicts. XCD chunk swizzle (n-inner) for A L2 reuse.
enum { EPI_QKV = 0, EPI_PROJ = 1, EPI_GELU = 2, EPI_FC2 = 3 };

template <int EPI>
__global__ __launch_bounds__(512, 2) void k_gemm3(
    const u16* __restrict__ A, const u16* __restrict__ Bw,
    const float* __restrict__ bias, u16* __restrict__ obf,
    float* __restrict__ of32, const float* __restrict__ addsrc,
    int K, int lda, int ldb, int ldc, int NT) {
  __shared__ u16 As[256 * 64];  // 32 KB
  __shared__ u16 Bs[128 * 64];  // 16 KB
  // bijective XCD chunk swizzle (m204), n-inner for A-panel L2 reuse
  const int nwg = gridDim.x;
  const int q = nwg >> 3, r = nwg & 7;
  const int xcd = blockIdx.x & 7, rank = blockIdx.x >> 3;
  const int swz = (xcd < r ? xcd * (q + 1) : r * (q + 1) + (xcd - r) * q) + rank;
  const int m0 = (swz / NT) * 256, n0 = (swz % NT) * 128;

  const int tid = threadIdx.x;
  const int wid = tid >> 6, lane = tid & 63;
  const int wr = wid >> 1, wc = wid & 1;  // 4M x 2N waves, per-wave 64x64

  // staging: pre-swizzled global source; linear LDS dest (HW adds lane*16B)
  const int srow = tid >> 3;                      // 0..63
  const int scol = 8 * ((tid & 7) ^ (srow & 7));  // inverse-swizzled col
  const size_t abase = (size_t)(m0 + srow) * lda + scol;
  const size_t bbase = (size_t)(n0 + srow) * ldb + scol;
  const int dbase = wid * 512;  // (wid*8 rows)*64 u16

  f32x4 acc[4][4] = {};
  const int lrow = lane & 15;
  const int g8 = (lane >> 4) * 8;
  const int rx = (lrow & 7) << 3;  // read-side XOR (u16 units)

  const int NTK = K >> 6;

  for (int t = 0; t < NTK; ++t) {
    const int k0 = t << 6;
#pragma unroll
    for (int i = 0; i < 4; ++i)
      gl_lds16(A + abase + (size_t)(i * 64) * lda + k0,
               As + i * 4096 + dbase);
#pragma unroll
    for (int i = 0; i < 2; ++i)
      gl_lds16(Bw + bbase + (size_t)(i * 64) * ldb + k0,
               Bs + i * 4096 + dbase);
    __syncthreads();  // drains vmcnt/lgkm + barrier
    __builtin_amdgcn_s_setprio(1);
#pragma unroll
    for (int kk = 0; kk < 64; kk += 32) {
      bf16x8 af[4], bf[4];
#pragma unroll
      for (int mi = 0; mi < 4; ++mi) {
        int row = wr * 64 + mi * 16 + lrow;
        af[mi] = *(const bf16x8*)(&As[row * 64 + ((kk + g8) ^ rx)]);
      }
#pragma unroll
      for (int ni = 0; ni < 4; ++ni) {
        int row = wc * 64 + ni * 16 + lrow;
        bf[ni] = *(const bf16x8*)(&Bs[row * 64 + ((kk + g8) ^ rx)]);
      }
#pragma unroll
      for (int mi = 0; mi < 4; ++mi)
#pragma unroll
        for (int ni = 0; ni < 4; ++ni)
          acc[mi][ni] = __builtin_amdgcn_mfma_f32_16x16x32_bf16(
              af[mi], bf[ni], acc[mi][ni], 0, 0, 0);
    }
    __builtin_amdgcn_s_setprio(0);
    __syncthreads();  // protect buffers before next stage
  }

  // epilogue: D mapping col=lane&15, row=(lane>>4)*4+reg
  const int erow = (lane >> 4) * 4;
  const int ecol = lane & 15;
#pragma unroll
  for (int mi = 0; mi < 4; ++mi) {
#pragma unroll
    for (int ni = 0; ni < 4; ++ni) {
      int gcol = n0 + wc * 64 + ni * 16 + ecol;
      float bv = bias[gcol];
#pragma unroll
      for (int r4 = 0; r4 < 4; ++r4) {
        int grow = m0 + wr * 64 + mi * 16 + erow + r4;
        float v = acc[mi][ni][r4] + bv;
        if (EPI == EPI_QKV) {
          // fold attention scale 1/sqrt(32) into q columns (cols < 384)
          float vv = (gcol < 384) ? v * 0.17677669529663689f : v;
          obf[(size_t)grow * ldc + gcol] = f2bf(vv);
        } else if (EPI == EPI_GELU) {
          obf[(size_t)grow * ldc + gcol] = f2bf(gelu_fast(v));
        } else if (EPI == EPI_PROJ) {
          int nwin = grow / 49, l = grow % 49;
          int bb = nwin >> 6, wi = nwin & 63;
          int wh = wi >> 3, ww = wi & 7;
          int rr = l / 7, cc = l % 7;
          int sr = wh * 7 + rr + 3; if (sr >= 56) sr -= 56;
          int sc = ww * 7 + cc + 3; if (sc >= 56) sc -= 56;
          size_t idx = ((size_t)(bb * 3136 + sr * 56 + sc)) * 384 + gcol;
          of32[idx] = addsrc[idx] + v;
        } else {  // EPI_FC2: accumulate into (row-chunked) d_out
          size_t idx = (size_t)grow * 384 + gcol;
          of32[idx] = of32[idx] + v;
        }
      }
    }
  }
}

// ---------------- MFMA windowed attention v2 (R8-proven) ------------------
__global__ __launch_bounds__(64) void k_attn2(const u16* __restrict__ qkv,
                                              const float* __restrict__ tbl,
                                              u16* __restrict__ out) {
  __shared__ u16 P[64 * 64];  // 8KB, wave-private
  const int bx = blockIdx.x;
  const int n = bx / 12, h = bx - n * 12;
  const int lane = threadIdx.x & 63;
  const int g = lane >> 4, c = lane & 15;
  const u16* base = qkv + (size_t)n * 56448 + h * 32;
  const int wi = n & 63;
  const int wt = (((wi >> 3) == 7) ? 2 : 0) | (((wi & 7) == 7) ? 1 : 0);
  const float* T = tbl + (size_t)((h << 2) | wt) * 4096;

  f32x4 st[4][4];  // [kj][qi]; reg r -> j = kj*16+g*4+r, i = qi*16+c
#pragma unroll
  for (int kj = 0; kj < 4; ++kj)
#pragma unroll
    for (int qi = 0; qi < 4; ++qi)
#pragma unroll
      for (int r = 0; r < 4; ++r)
        st[kj][qi][r] = T[(kj * 16 + g * 4 + r) * 64 + qi * 16 + c];

  bf16x8 qf[4], kf[4];
#pragma unroll
  for (int t = 0; t < 4; ++t) {
    int row = t * 16 + c; if (row > 48) row = 48;
    qf[t] = *(const bf16x8*)(base + (size_t)row * 1152 + g * 8);
    kf[t] = *(const bf16x8*)(base + (size_t)row * 1152 + 384 + g * 8);
  }

#pragma unroll
  for (int kj = 0; kj < 4; ++kj)
#pragma unroll
    for (int qi = 0; qi < 4; ++qi)
      st[kj][qi] = __builtin_amdgcn_mfma_f32_16x16x32_bf16(kf[kj], qf[qi],
                                                           st[kj][qi], 0, 0, 0);

#pragma unroll
  for (int qi = 0; qi < 4; ++qi) {
    float m = -3e38f;
#pragma unroll
    for (int kj = 0; kj < 4; ++kj)
#pragma unroll
      for (int r = 0; r < 4; ++r) m = fmaxf(m, st[kj][qi][r]);
    m = fmaxf(m, __shfl_xor(m, 16));
    m = fmaxf(m, __shfl_xor(m, 32));
    float sum = 0.f;
#pragma unroll
    for (int kj = 0; kj < 4; ++kj)
#pragma unroll
      for (int r = 0; r < 4; ++r) {
        float e = __expf(st[kj][qi][r] - m);
        st[kj][qi][r] = e;
        sum += e;
      }
    sum += __shfl_xor(sum, 16);
    sum += __shfl_xor(sum, 32);
    float inv = 1.f / sum;
    int i = qi * 16 + c;
#pragma unroll
    for (int kj = 0; kj < 4; ++kj)
#pragma unroll
      for (int hh = 0; hh < 2; ++hh) {
        u32 pk = (u32)f2bf(st[kj][qi][2 * hh] * inv) |
                 ((u32)f2bf(st[kj][qi][2 * hh + 1] * inv) << 16);
        int idx = (i * 64 + kj * 16 + g * 4 + 2 * hh) ^ ((i & 7) << 3);
        *(u32*)(P + idx) = pk;
      }
  }

  f32x4 o[4][2] = {};
#pragma unroll
  for (int k0 = 0; k0 < 2; ++k0) {
    bf16x8 pa[4], vb[2];
#pragma unroll
    for (int qi = 0; qi < 4; ++qi) {
      int qq = qi * 16 + c;
      pa[qi] = *(const bf16x8*)(P + ((qq * 64 + k0 * 32 + g * 8) ^ ((qq & 7) << 3)));
    }
#pragma unroll
    for (int ni = 0; ni < 2; ++ni) {
      union { bf16x8 v; u16 a[8]; } vu;
#pragma unroll
      for (int e = 0; e < 8; ++e) {
        int j = k0 * 32 + g * 8 + e;
        int jr = j > 48 ? 48 : j;
        vu.a[e] = base[(size_t)jr * 1152 + 768 + ni * 16 + c];
      }
      vb[ni] = vu.v;
#pragma unroll
      for (int qi = 0; qi < 4; ++qi)
        o[qi][ni] = __builtin_amdgcn_mfma_f32_16x16x32_bf16(pa[qi], vb[ni],
                                                            o[qi][ni], 0, 0, 0);
    }
  }

  u16* ob = out + (size_t)n * 18816 + h * 32;
#pragma unroll
  for (int qi = 0; qi < 4; ++qi)
#pragma unroll
    for (int r = 0; r < 4; ++r) {
      int qq = qi * 16 + g * 4 + r;
      if (qq < 49) {
#pragma unroll
        for (int ni = 0; ni < 2; ++ni)
          ob[(size_t)qq * 384 + ni * 16 + c] = f2bf(o[qi][ni][r]);
      }
    }
}

// --------------------------------------------------------------------------
extern "C" void kernel_launch(void* const* d_in, const int* in_sizes, int n_in,
                              void* d_out, int out_size, void* d_ws,
                              size_t ws_size, hipStream_t stream) {
  const float* hidden = (const float*)d_in[0];
  const float* ln1g = (const float*)d_in[1];
  const float* ln1b = (const float*)d_in[2];
  const float* qkvw = (const float*)d_in[3];
  const float* qkvb = (const float*)d_in[4];
  const float* outw = (const float*)d_in[5];
  const float* outb = (const float*)d_in[6];
  const float* relt = (const float*)d_in[7];
  const float* ln2g = (const float*)d_in[8];
  const float* ln2b = (const float*)d_in[9];
  const float* fc1w = (const float*)d_in[10];
  const float* fc1b = (const float*)d_in[11];
  const float* fc2w = (const float*)d_in[12];
  const float* fc2b = (const float*)d_in[13];
  float* out = (float*)d_out;

  u16* wq = (u16*)d_ws;            // 1152*384 (dead after qkv GEMM -> tbl)
  u16* wo = wq + 442368;           // 384*384
  u16* w1 = wo + 147456;           // 1536*384
  u16* w2 = w1 + 589824;           // 384*1536
  u16* xw = w2 + 589824;           // 100352*384  (also attn_out)
  u16* qkv = xw + 38535168;        // 100352*1152 (region reused below)
  u16* xn = qkv;                   // 100352*384
  u16* hbuf = xn + 38535168;       // 50176*1536 (row-half MLP buffer)
  float* tbl = (float*)wq;         // 196608 f32 <= wq region (221184 f32)

  // all 4 weight converts in one launch
  k_f2bf4<<<6912, 256, 0, stream>>>(qkvw, outw, fc1w, fc2w, wq, wo, w1, w2);

  // LN1 + shift + window partition
  k_ln<1><<<25088, 256, 0, stream>>>(hidden, ln1g, ln1b, xw);

  // qkv = xw @ qkv_w^T + b  (q cols pre-scaled by 1/sqrt(32))
  k_gemm3<EPI_QKV><<<392 * 9, 512, 0, stream>>>(
      xw, wq, qkvb, qkv, nullptr, nullptr, 384, 384, 384, 1152, 9);

  // bias+mask tables into the now-dead wq region
  k_tbl<<<768, 256, 0, stream>>>(relt, tbl);

  // MFMA attention (writes attn_out into xw buffer)
  k_attn2<<<24576, 64, 0, stream>>>(qkv, tbl, xw);

  // out proj + window reverse + unshift + residual -> d_out (= x)
  k_gemm3<EPI_PROJ><<<392 * 3, 512, 0, stream>>>(
      xw, wo, outb, nullptr, out, hidden, 384, 384, 384, 384, 3);

  // LN2
  k_ln<0><<<25088, 256, 0, stream>>>(out, ln2g, ln2b, xn);

  // MLP, M-chunked (two row-halves), full N=1536 / K=1536
  for (int ch = 0; ch < 2; ++ch) {
    const u16* xa = xn + (size_t)ch * 50176 * 384;
    float* oc = out + (size_t)ch * 50176 * 384;
    k_gemm3<EPI_GELU><<<196 * 12, 512, 0, stream>>>(
        xa, w1, fc1b, hbuf, nullptr, nullptr, 384, 384, 384, 1536, 12);
    k_gemm3<EPI_FC2><<<196 * 3, 512, 0, stream>>>(
        hbuf, w2, fc2b, nullptr, oc, nullptr, 1536, 1536, 1536, 384, 3);
  }
}

// Round 14
// 905.298 us; speedup vs baseline: 1.0543x; 1.0024x over previous
//
#include <hip/hip_runtime.h>
#include <cstdint>
#include <cstddef>

using u16 = unsigned short;
using u32 = unsigned int;

typedef __attribute__((ext_vector_type(8))) short bf16x8;
typedef __attribute__((ext_vector_type(4))) float f32x4;

__device__ __forceinline__ u16 f2bf(float f) {
  union { float f; u32 u; } v; v.f = f;
  u32 r = v.u + 0x7FFFu + ((v.u >> 16) & 1u);
  return (u16)(r >> 16);
}
__device__ __forceinline__ float bf2f(u16 h) {
  union { u32 u; float f; } v; v.u = ((u32)h) << 16;
  return v.f;
}

__device__ __forceinline__ void gl_lds16(const void* g, void* l) {
  __builtin_amdgcn_global_load_lds(
      (const __attribute__((address_space(1))) void*)g,
      (__attribute__((address_space(3))) void*)l, 16, 0, 0);
}

// tanh-form GELU via exp (≈13 VALU ops vs ~25 for erff; |Δ| ≤ ~1e-3)
__device__ __forceinline__ float gelu_fast(float v) {
  float u = v * (0.7978845608f + 0.0356774081f * v * v);
  float e = __expf(-2.f * fabsf(u));
  float th = (1.f - e) / (1.f + e);
  th = (u >= 0.f) ? th : -th;
  return 0.5f * v * (1.f + th);
}

// ---------------- fp32 -> bf16 weight convert, all 4 weights fused -------
__global__ __launch_bounds__(256) void k_f2bf4(
    const float* __restrict__ a0, const float* __restrict__ a1,
    const float* __restrict__ a2, const float* __restrict__ a3,
    u16* __restrict__ d0, u16* __restrict__ d1, u16* __restrict__ d2,
    u16* __restrict__ d3) {
  int i = blockIdx.x * 256 + threadIdx.x;
  if (i < 442368) d0[i] = f2bf(a0[i]);
  else if (i < 589824) d1[i - 442368] = f2bf(a1[i - 442368]);
  else if (i < 1179648) d2[i - 589824] = f2bf(a2[i - 589824]);
  else if (i < 1769472) d3[i - 1179648] = f2bf(a3[i - 1179648]);
}

// ---------------- combined rel-bias + shift-mask + pad tables v2 ----------
// Lane-vectorized layout: tbl[(h*4+wt)][kj][r][g][c][qi] (4096 f32 per
// (h,wt)). Lane (g,c) loads one float4 (qi=0..3) per (kj,r): 16-lane group
// reads 256B contiguous. i(query)=qi*16+c, j(key)=kj*16+g*4+r; j>=49 -> -3e38
__global__ __launch_bounds__(256) void k_tbl(const float* __restrict__ relt,
                                             float* __restrict__ tbl) {
  int id = blockIdx.x * 256 + threadIdx.x;
  if (id >= 196608) return;
  int qi = id & 3, c = (id >> 2) & 15, g = (id >> 6) & 3;
  int r = (id >> 8) & 3, kj = (id >> 10) & 3;
  int wt = (id >> 12) & 3, h = id >> 14;
  int i = qi * 16 + c;          // query index 0..63
  int j = kj * 16 + g * 4 + r;  // key index 0..63
  float v;
  if (j >= 49) {
    v = -3e38f;
  } else {
    int ii = i < 49 ? i : 48;
    int r1 = ii / 7, c1 = ii % 7, r2 = j / 7, c2 = j % 7;
    v = relt[((r1 - r2 + 6) * 13 + (c1 - c2 + 6)) * 12 + h];
    int rr1 = (wt & 2) ? (r1 < 4 ? 1 : 2) : 0;
    int rr2 = (wt & 2) ? (r2 < 4 ? 1 : 2) : 0;
    int cc1 = (wt & 1) ? (c1 < 4 ? 1 : 2) : 0;
    int cc2 = (wt & 1) ? (c2 < 4 ? 1 : 2) : 0;
    if (rr1 != rr2 || cc1 != cc2) v -= 100.f;
  }
  tbl[id] = v;
}

// ---------------- LayerNorm (optionally fused shift+window gather) -------
template <int GATHER>
__global__ __launch_bounds__(256) void k_ln(const float* __restrict__ x,
                                            const float* __restrict__ g,
                                            const float* __restrict__ b,
                                            u16* __restrict__ out) {
  int wave = threadIdx.x >> 6, lane = threadIdx.x & 63;
  int idx = blockIdx.x * 4 + wave;  // output token index
  int src;
  if (GATHER) {
    int n = idx / 49, l = idx % 49;
    int bb = n >> 6, wi = n & 63;
    int wh = wi >> 3, ww = wi & 7;
    int r = l / 7, c = l % 7;
    int sr = wh * 7 + r + 3; if (sr >= 56) sr -= 56;
    int sc = ww * 7 + c + 3; if (sc >= 56) sc -= 56;
    src = bb * 3136 + sr * 56 + sc;
  } else {
    src = idx;
  }
  const float* xi = x + (size_t)src * 384;
  float2 v[3];
  float s = 0.f, sq = 0.f;
#pragma unroll
  for (int p = 0; p < 3; ++p) {
    v[p] = *(const float2*)(xi + p * 128 + lane * 2);
    s += v[p].x + v[p].y;
    sq += v[p].x * v[p].x + v[p].y * v[p].y;
  }
#pragma unroll
  for (int o = 32; o; o >>= 1) {
    s += __shfl_xor(s, o);
    sq += __shfl_xor(sq, o);
  }
  float mu = s * (1.f / 384.f);
  float var = sq * (1.f / 384.f) - mu * mu;
  float rstd = rsqrtf(var + 1e-5f);
  u16* oo = out + (size_t)idx * 384;
#pragma unroll
  for (int p = 0; p < 3; ++p) {
    int e = p * 128 + lane * 2;
    u16 o0 = f2bf((v[p].x - mu) * rstd * g[e] + b[e]);
    u16 o1 = f2bf((v[p].y - mu) * rstd * g[e + 1] + b[e + 1]);
    u32 pk = (u32)o0 | ((u32)o1 << 16);
    *(u32*)(oo + e) = pk;
  }
}

// ---------------- GEMM (R8-proven): 256x128 tile, 8 waves, single-buffer --
// stage -> __syncthreads -> compute -> __syncthreads. T2 XOR-swizzle
// both-sides -> 0 bank conflicts. XCD chunk swizzle (n-inner) for A L2 reuse.
enum { EPI_QKV = 0, EPI_PROJ = 1, EPI_GELU = 2, EPI_FC2 = 3 };

template <int EPI>
__global__ __launch_bounds__(512, 2) void k_gemm3(
    const u16* __restrict__ A, const u16* __restrict__ Bw,
    const float* __restrict__ bias, u16* __restrict__ obf,
    float* __restrict__ of32, const float* __restrict__ addsrc,
    int K, int lda, int ldb, int ldc, int NT) {
  __shared__ u16 As[256 * 64];  // 32 KB
  __shared__ u16 Bs[128 * 64];  // 16 KB
  // bijective XCD chunk swizzle (m204), n-inner for A-panel L2 reuse
  const int nwg = gridDim.x;
  const int q = nwg >> 3, r = nwg & 7;
  const int xcd = blockIdx.x & 7, rank = blockIdx.x >> 3;
  const int swz = (xcd < r ? xcd * (q + 1) : r * (q + 1) + (xcd - r) * q) + rank;
  const int m0 = (swz / NT) * 256, n0 = (swz % NT) * 128;

  const int tid = threadIdx.x;
  const int wid = tid >> 6, lane = tid & 63;
  const int wr = wid >> 1, wc = wid & 1;  // 4M x 2N waves, per-wave 64x64

  // staging: pre-swizzled global source; linear LDS dest (HW adds lane*16B)
  const int srow = tid >> 3;                      // 0..63
  const int scol = 8 * ((tid & 7) ^ (srow & 7));  // inverse-swizzled col
  const size_t abase = (size_t)(m0 + srow) * lda + scol;
  const size_t bbase = (size_t)(n0 + srow) * ldb + scol;
  const int dbase = wid * 512;  // (wid*8 rows)*64 u16

  f32x4 acc[4][4] = {};
  const int lrow = lane & 15;
  const int g8 = (lane >> 4) * 8;
  const int rx = (lrow & 7) << 3;  // read-side XOR (u16 units)

  const int NTK = K >> 6;

  for (int t = 0; t < NTK; ++t) {
    const int k0 = t << 6;
#pragma unroll
    for (int i = 0; i < 4; ++i)
      gl_lds16(A + abase + (size_t)(i * 64) * lda + k0,
               As + i * 4096 + dbase);
#pragma unroll
    for (int i = 0; i < 2; ++i)
      gl_lds16(Bw + bbase + (size_t)(i * 64) * ldb + k0,
               Bs + i * 4096 + dbase);
    __syncthreads();  // drains vmcnt/lgkm + barrier
    __builtin_amdgcn_s_setprio(1);
#pragma unroll
    for (int kk = 0; kk < 64; kk += 32) {
      bf16x8 af[4], bf[4];
#pragma unroll
      for (int mi = 0; mi < 4; ++mi) {
        int row = wr * 64 + mi * 16 + lrow;
        af[mi] = *(const bf16x8*)(&As[row * 64 + ((kk + g8) ^ rx)]);
      }
#pragma unroll
      for (int ni = 0; ni < 4; ++ni) {
        int row = wc * 64 + ni * 16 + lrow;
        bf[ni] = *(const bf16x8*)(&Bs[row * 64 + ((kk + g8) ^ rx)]);
      }
#pragma unroll
      for (int mi = 0; mi < 4; ++mi)
#pragma unroll
        for (int ni = 0; ni < 4; ++ni)
          acc[mi][ni] = __builtin_amdgcn_mfma_f32_16x16x32_bf16(
              af[mi], bf[ni], acc[mi][ni], 0, 0, 0);
    }
    __builtin_amdgcn_s_setprio(0);
    __syncthreads();  // protect buffers before next stage
  }

  // epilogue: D mapping col=lane&15, row=(lane>>4)*4+reg
  const int erow = (lane >> 4) * 4;
  const int ecol = lane & 15;
#pragma unroll
  for (int mi = 0; mi < 4; ++mi) {
#pragma unroll
    for (int ni = 0; ni < 4; ++ni) {
      int gcol = n0 + wc * 64 + ni * 16 + ecol;
      float bv = bias[gcol];
#pragma unroll
      for (int r4 = 0; r4 < 4; ++r4) {
        int grow = m0 + wr * 64 + mi * 16 + erow + r4;
        float v = acc[mi][ni][r4] + bv;
        if (EPI == EPI_QKV) {
          // fold attention scale 1/sqrt(32) into q columns (cols < 384)
          float vv = (gcol < 384) ? v * 0.17677669529663689f : v;
          obf[(size_t)grow * ldc + gcol] = f2bf(vv);
        } else if (EPI == EPI_GELU) {
          obf[(size_t)grow * ldc + gcol] = f2bf(gelu_fast(v));
        } else if (EPI == EPI_PROJ) {
          int nwin = grow / 49, l = grow % 49;
          int bb = nwin >> 6, wi = nwin & 63;
          int wh = wi >> 3, ww = wi & 7;
          int rr = l / 7, cc = l % 7;
          int sr = wh * 7 + rr + 3; if (sr >= 56) sr -= 56;
          int sc = ww * 7 + cc + 3; if (sc >= 56) sc -= 56;
          size_t idx = ((size_t)(bb * 3136 + sr * 56 + sc)) * 384 + gcol;
          of32[idx] = addsrc[idx] + v;
        } else {  // EPI_FC2: accumulate into (row-chunked) d_out
          size_t idx = (size_t)grow * 384 + gcol;
          of32[idx] = of32[idx] + v;
        }
      }
    }
  }
}

// ---------------- MFMA windowed attention v4 ------------------------------
// v2 + vectorized table C-init (16 coalesced float4 loads/lane from the
// lane-major tbl2 layout) + setprio around MFMA clusters (m191: helps for
// independent 1-wave blocks at different phases).
__global__ __launch_bounds__(64) void k_attn2(const u16* __restrict__ qkv,
                                              const float* __restrict__ tbl,
                                              u16* __restrict__ out) {
  __shared__ u16 P[64 * 64];  // 8KB, wave-private
  const int bx = blockIdx.x;
  const int n = bx / 12, h = bx - n * 12;
  const int lane = threadIdx.x & 63;
  const int g = lane >> 4, c = lane & 15;
  const u16* base = qkv + (size_t)n * 56448 + h * 32;
  const int wi = n & 63;
  const int wt = (((wi >> 3) == 7) ? 2 : 0) | (((wi & 7) == 7) ? 1 : 0);
  const float* T = tbl + (size_t)((h << 2) | wt) * 4096;

  // table C-init: one float4 per (kj,r) -> st[kj][qi][r] = v4[qi]
  f32x4 st[4][4];  // [kj][qi]; reg r -> j = kj*16+g*4+r, i = qi*16+c
#pragma unroll
  for (int kj = 0; kj < 4; ++kj)
#pragma unroll
    for (int r = 0; r < 4; ++r) {
      f32x4 v4 = *(const f32x4*)(T + ((((kj * 4 + r) * 4 + g) * 16 + c) << 2));
#pragma unroll
      for (int qi = 0; qi < 4; ++qi) st[kj][qi][r] = v4[qi];
    }

  bf16x8 qf[4], kf[4];
#pragma unroll
  for (int t = 0; t < 4; ++t) {
    int row = t * 16 + c; if (row > 48) row = 48;
    qf[t] = *(const bf16x8*)(base + (size_t)row * 1152 + g * 8);
    kf[t] = *(const bf16x8*)(base + (size_t)row * 1152 + 384 + g * 8);
  }

  __builtin_amdgcn_s_setprio(1);
#pragma unroll
  for (int kj = 0; kj < 4; ++kj)
#pragma unroll
    for (int qi = 0; qi < 4; ++qi)
      st[kj][qi] = __builtin_amdgcn_mfma_f32_16x16x32_bf16(kf[kj], qf[qi],
                                                           st[kj][qi], 0, 0, 0);
  __builtin_amdgcn_s_setprio(0);

#pragma unroll
  for (int qi = 0; qi < 4; ++qi) {
    float m = -3e38f;
#pragma unroll
    for (int kj = 0; kj < 4; ++kj)
#pragma unroll
      for (int r = 0; r < 4; ++r) m = fmaxf(m, st[kj][qi][r]);
    m = fmaxf(m, __shfl_xor(m, 16));
    m = fmaxf(m, __shfl_xor(m, 32));
    float sum = 0.f;
#pragma unroll
    for (int kj = 0; kj < 4; ++kj)
#pragma unroll
      for (int r = 0; r < 4; ++r) {
        float e = __expf(st[kj][qi][r] - m);
        st[kj][qi][r] = e;
        sum += e;
      }
    sum += __shfl_xor(sum, 16);
    sum += __shfl_xor(sum, 32);
    float inv = 1.f / sum;
    int i = qi * 16 + c;
#pragma unroll
    for (int kj = 0; kj < 4; ++kj)
#pragma unroll
      for (int hh = 0; hh < 2; ++hh) {
        u32 pk = (u32)f2bf(st[kj][qi][2 * hh] * inv) |
                 ((u32)f2bf(st[kj][qi][2 * hh + 1] * inv) << 16);
        int idx = (i * 64 + kj * 16 + g * 4 + 2 * hh) ^ ((i & 7) << 3);
        *(u32*)(P + idx) = pk;
      }
  }

  f32x4 o[4][2] = {};
#pragma unroll
  for (int k0 = 0; k0 < 2; ++k0) {
    bf16x8 pa[4], vb[2];
#pragma unroll
    for (int qi = 0; qi < 4; ++qi) {
      int qq = qi * 16 + c;
      pa[qi] = *(const bf16x8*)(P + ((qq * 64 + k0 * 32 + g * 8) ^ ((qq & 7) << 3)));
    }
#pragma unroll
    for (int ni = 0; ni < 2; ++ni) {
      union { bf16x8 v; u16 a[8]; } vu;
#pragma unroll
      for (int e = 0; e < 8; ++e) {
        int j = k0 * 32 + g * 8 + e;
        int jr = j > 48 ? 48 : j;
        vu.a[e] = base[(size_t)jr * 1152 + 768 + ni * 16 + c];
      }
      vb[ni] = vu.v;
    }
    __builtin_amdgcn_s_setprio(1);
#pragma unroll
    for (int ni = 0; ni < 2; ++ni)
#pragma unroll
      for (int qi = 0; qi < 4; ++qi)
        o[qi][ni] = __builtin_amdgcn_mfma_f32_16x16x32_bf16(pa[qi], vb[ni],
                                                            o[qi][ni], 0, 0, 0);
    __builtin_amdgcn_s_setprio(0);
  }

  u16* ob = out + (size_t)n * 18816 + h * 32;
#pragma unroll
  for (int qi = 0; qi < 4; ++qi)
#pragma unroll
    for (int r = 0; r < 4; ++r) {
      int qq = qi * 16 + g * 4 + r;
      if (qq < 49) {
#pragma unroll
        for (int ni = 0; ni < 2; ++ni)
          ob[(size_t)qq * 384 + ni * 16 + c] = f2bf(o[qi][ni][r]);
      }
    }
}

// --------------------------------------------------------------------------
extern "C" void kernel_launch(void* const* d_in, const int* in_sizes, int n_in,
                              void* d_out, int out_size, void* d_ws,
                              size_t ws_size, hipStream_t stream) {
  const float* hidden = (const float*)d_in[0];
  const float* ln1g = (const float*)d_in[1];
  const float* ln1b = (const float*)d_in[2];
  const float* qkvw = (const float*)d_in[3];
  const float* qkvb = (const float*)d_in[4];
  const float* outw = (const float*)d_in[5];
  const float* outb = (const float*)d_in[6];
  const float* relt = (const float*)d_in[7];
  const float* ln2g = (const float*)d_in[8];
  const float* ln2b = (const float*)d_in[9];
  const float* fc1w = (const float*)d_in[10];
  const float* fc1b = (const float*)d_in[11];
  const float* fc2w = (const float*)d_in[12];
  const float* fc2b = (const float*)d_in[13];
  float* out = (float*)d_out;

  u16* wq = (u16*)d_ws;            // 1152*384 (dead after qkv GEMM -> tbl)
  u16* wo = wq + 442368;           // 384*384
  u16* w1 = wo + 147456;           // 1536*384
  u16* w2 = w1 + 589824;           // 384*1536
  u16* xw = w2 + 589824;           // 100352*384  (also attn_out)
  u16* qkv = xw + 38535168;        // 100352*1152 (region reused below)
  u16* xn = qkv;                   // 100352*384
  u16* hbuf = xn + 38535168;       // 50176*1536 (row-half MLP buffer)
  float* tbl = (float*)wq;         // 196608 f32 <= wq region (221184 f32)

  // all 4 weight converts in one launch
  k_f2bf4<<<6912, 256, 0, stream>>>(qkvw, outw, fc1w, fc2w, wq, wo, w1, w2);

  // LN1 + shift + window partition
  k_ln<1><<<25088, 256, 0, stream>>>(hidden, ln1g, ln1b, xw);

  // qkv = xw @ qkv_w^T + b  (q cols pre-scaled by 1/sqrt(32))
  k_gemm3<EPI_QKV><<<392 * 9, 512, 0, stream>>>(
      xw, wq, qkvb, qkv, nullptr, nullptr, 384, 384, 384, 1152, 9);

  // bias+mask tables (lane-major layout) into the now-dead wq region
  k_tbl<<<768, 256, 0, stream>>>(relt, tbl);

  // MFMA attention (writes attn_out into xw buffer)
  k_attn2<<<24576, 64, 0, stream>>>(qkv, tbl, xw);

  // out proj + window reverse + unshift + residual -> d_out (= x)
  k_gemm3<EPI_PROJ><<<392 * 3, 512, 0, stream>>>(
      xw, wo, outb, nullptr, out, hidden, 384, 384, 384, 384, 3);

  // LN2
  k_ln<0><<<25088, 256, 0, stream>>>(out, ln2g, ln2b, xn);

  // MLP, M-chunked (two row-halves), full N=1536 / K=1536
  for (int ch = 0; ch < 2; ++ch) {
    const u16* xa = xn + (size_t)ch * 50176 * 384;
    float* oc = out + (size_t)ch * 50176 * 384;
    k_gemm3<EPI_GELU><<<196 * 12, 512, 0, stream>>>(
        xa, w1, fc1b, hbuf, nullptr, nullptr, 384, 384, 384, 1536, 12);
    k_gemm3<EPI_FC2><<<196 * 3, 512, 0, stream>>>(
        hbuf, w2, fc2b, nullptr, oc, nullptr, 1536, 1536, 1536, 384, 3);
  }
}

// Round 15
// 858.337 us; speedup vs baseline: 1.1119x; 1.0547x over previous
//
#include <hip/hip_runtime.h>
#include <cstdint>
#include <cstddef>

using u16 = unsigned short;
using u32 = unsigned int;

typedef __attribute__((ext_vector_type(8))) short bf16x8;
typedef __attribute__((ext_vector_type(4))) float f32x4;

__device__ __forceinline__ u16 f2bf(float f) {
  union { float f; u32 u; } v; v.f = f;
  u32 r = v.u + 0x7FFFu + ((v.u >> 16) & 1u);
  return (u16)(r >> 16);
}
__device__ __forceinline__ float bf2f(u16 h) {
  union { u32 u; float f; } v; v.u = ((u32)h) << 16;
  return v.f;
}

__device__ __forceinline__ void gl_lds16(const void* g, void* l) {
  __builtin_amdgcn_global_load_lds(
      (const __attribute__((address_space(1))) void*)g,
      (__attribute__((address_space(3))) void*)l, 16, 0, 0);
}

// tanh-form GELU via exp (≈13 VALU ops vs ~25 for erff; |Δ| ≤ ~1e-3)
__device__ __forceinline__ float gelu_fast(float v) {
  float u = v * (0.7978845608f + 0.0356774081f * v * v);
  float e = __expf(-2.f * fabsf(u));
  float th = (1.f - e) / (1.f + e);
  th = (u >= 0.f) ? th : -th;
  return 0.5f * v * (1.f + th);
}

// ---------------- fp32 -> bf16 weight convert, all 4 weights fused -------
__global__ __launch_bounds__(256) void k_f2bf4(
    const float* __restrict__ a0, const float* __restrict__ a1,
    const float* __restrict__ a2, const float* __restrict__ a3,
    u16* __restrict__ d0, u16* __restrict__ d1, u16* __restrict__ d2,
    u16* __restrict__ d3) {
  int i = blockIdx.x * 256 + threadIdx.x;
  if (i < 442368) d0[i] = f2bf(a0[i]);
  else if (i < 589824) d1[i - 442368] = f2bf(a1[i - 442368]);
  else if (i < 1179648) d2[i - 589824] = f2bf(a2[i - 589824]);
  else if (i < 1769472) d3[i - 1179648] = f2bf(a3[i - 1179648]);
}

// ---------------- combined rel-bias + shift-mask + pad tables (lane-major) -
// tbl[(h*4+wt)][kj][r][g][c][qi]; i(query)=qi*16+c, j(key)=kj*16+g*4+r
__global__ __launch_bounds__(256) void k_tbl(const float* __restrict__ relt,
                                             float* __restrict__ tbl) {
  int id = blockIdx.x * 256 + threadIdx.x;
  if (id >= 196608) return;
  int qi = id & 3, c = (id >> 2) & 15, g = (id >> 6) & 3;
  int r = (id >> 8) & 3, kj = (id >> 10) & 3;
  int wt = (id >> 12) & 3, h = id >> 14;
  int i = qi * 16 + c;
  int j = kj * 16 + g * 4 + r;
  float v;
  if (j >= 49) {
    v = -3e38f;
  } else {
    int ii = i < 49 ? i : 48;
    int r1 = ii / 7, c1 = ii % 7, r2 = j / 7, c2 = j % 7;
    v = relt[((r1 - r2 + 6) * 13 + (c1 - c2 + 6)) * 12 + h];
    int rr1 = (wt & 2) ? (r1 < 4 ? 1 : 2) : 0;
    int rr2 = (wt & 2) ? (r2 < 4 ? 1 : 2) : 0;
    int cc1 = (wt & 1) ? (c1 < 4 ? 1 : 2) : 0;
    int cc2 = (wt & 1) ? (c2 < 4 ? 1 : 2) : 0;
    if (rr1 != rr2 || cc1 != cc2) v -= 100.f;
  }
  tbl[id] = v;
}

// ---------------- LayerNorm fp32-in (optionally fused shift+window gather) -
template <int GATHER>
__global__ __launch_bounds__(256) void k_ln(const float* __restrict__ x,
                                            const float* __restrict__ g,
                                            const float* __restrict__ b,
                                            u16* __restrict__ out) {
  int wave = threadIdx.x >> 6, lane = threadIdx.x & 63;
  int idx = blockIdx.x * 4 + wave;
  int src;
  if (GATHER) {
    int n = idx / 49, l = idx % 49;
    int bb = n >> 6, wi = n & 63;
    int wh = wi >> 3, ww = wi & 7;
    int r = l / 7, c = l % 7;
    int sr = wh * 7 + r + 3; if (sr >= 56) sr -= 56;
    int sc = ww * 7 + c + 3; if (sc >= 56) sc -= 56;
    src = bb * 3136 + sr * 56 + sc;
  } else {
    src = idx;
  }
  const float* xi = x + (size_t)src * 384;
  float2 v[3];
  float s = 0.f, sq = 0.f;
#pragma unroll
  for (int p = 0; p < 3; ++p) {
    v[p] = *(const float2*)(xi + p * 128 + lane * 2);
    s += v[p].x + v[p].y;
    sq += v[p].x * v[p].x + v[p].y * v[p].y;
  }
#pragma unroll
  for (int o = 32; o; o >>= 1) {
    s += __shfl_xor(s, o);
    sq += __shfl_xor(sq, o);
  }
  float mu = s * (1.f / 384.f);
  float var = sq * (1.f / 384.f) - mu * mu;
  float rstd = rsqrtf(var + 1e-5f);
  u16* oo = out + (size_t)idx * 384;
#pragma unroll
  for (int p = 0; p < 3; ++p) {
    int e = p * 128 + lane * 2;
    u16 o0 = f2bf((v[p].x - mu) * rstd * g[e] + b[e]);
    u16 o1 = f2bf((v[p].y - mu) * rstd * g[e + 1] + b[e + 1]);
    u32 pk = (u32)o0 | ((u32)o1 << 16);
    *(u32*)(oo + e) = pk;
  }
}

// ---------------- LayerNorm bf16-in (for x stored as bf16) ----------------
__global__ __launch_bounds__(256) void k_ln_bf(const u16* __restrict__ x,
                                               const float* __restrict__ g,
                                               const float* __restrict__ b,
                                               u16* __restrict__ out) {
  int wave = threadIdx.x >> 6, lane = threadIdx.x & 63;
  int idx = blockIdx.x * 4 + wave;
  const u16* xi = x + (size_t)idx * 384;
  float v[6];
  float s = 0.f, sq = 0.f;
#pragma unroll
  for (int p = 0; p < 3; ++p) {
    u32 pk = *(const u32*)(xi + p * 128 + lane * 2);
    float a = bf2f((u16)(pk & 0xffff));
    float c2 = bf2f((u16)(pk >> 16));
    v[2 * p] = a; v[2 * p + 1] = c2;
    s += a + c2;
    sq += a * a + c2 * c2;
  }
#pragma unroll
  for (int o = 32; o; o >>= 1) {
    s += __shfl_xor(s, o);
    sq += __shfl_xor(sq, o);
  }
  float mu = s * (1.f / 384.f);
  float var = sq * (1.f / 384.f) - mu * mu;
  float rstd = rsqrtf(var + 1e-5f);
  u16* oo = out + (size_t)idx * 384;
#pragma unroll
  for (int p = 0; p < 3; ++p) {
    int e = p * 128 + lane * 2;
    u16 o0 = f2bf((v[2 * p] - mu) * rstd * g[e] + b[e]);
    u16 o1 = f2bf((v[2 * p + 1] - mu) * rstd * g[e + 1] + b[e + 1]);
    u32 pk = (u32)o0 | ((u32)o1 << 16);
    *(u32*)(oo + e) = pk;
  }
}

// ---------------- GEMM (R8-proven): 256x128 tile, 8 waves, single-buffer --
// stage -> __syncthreads -> compute -> __syncthreads. T2 XOR-swizzle
// both-sides -> 0 bank conflicts. XCD chunk swizzle (n-inner) for A L2 reuse.
// EPI_PROJ: x = hidden + proj  -> bf16 xbuf (window-reverse scatter).
// EPI_FC2:  out = bf2f(x) + mlp -> fp32 d_out (single full write).
enum { EPI_QKV = 0, EPI_PROJ = 1, EPI_GELU = 2, EPI_FC2 = 3 };

template <int EPI>
__global__ __launch_bounds__(512, 2) void k_gemm3(
    const u16* __restrict__ A, const u16* __restrict__ Bw,
    const float* __restrict__ bias, u16* __restrict__ obf,
    float* __restrict__ of32, const float* __restrict__ addsrc,
    const u16* __restrict__ xres, int K, int lda, int ldb, int ldc, int NT) {
  __shared__ u16 As[256 * 64];  // 32 KB
  __shared__ u16 Bs[128 * 64];  // 16 KB
  const int nwg = gridDim.x;
  const int q = nwg >> 3, r = nwg & 7;
  const int xcd = blockIdx.x & 7, rank = blockIdx.x >> 3;
  const int swz = (xcd < r ? xcd * (q + 1) : r * (q + 1) + (xcd - r) * q) + rank;
  const int m0 = (swz / NT) * 256, n0 = (swz % NT) * 128;

  const int tid = threadIdx.x;
  const int wid = tid >> 6, lane = tid & 63;
  const int wr = wid >> 1, wc = wid & 1;  // 4M x 2N waves, per-wave 64x64

  const int srow = tid >> 3;                      // 0..63
  const int scol = 8 * ((tid & 7) ^ (srow & 7));  // inverse-swizzled col
  const size_t abase = (size_t)(m0 + srow) * lda + scol;
  const size_t bbase = (size_t)(n0 + srow) * ldb + scol;
  const int dbase = wid * 512;

  f32x4 acc[4][4] = {};
  const int lrow = lane & 15;
  const int g8 = (lane >> 4) * 8;
  const int rx = (lrow & 7) << 3;

  const int NTK = K >> 6;

  for (int t = 0; t < NTK; ++t) {
    const int k0 = t << 6;
#pragma unroll
    for (int i = 0; i < 4; ++i)
      gl_lds16(A + abase + (size_t)(i * 64) * lda + k0,
               As + i * 4096 + dbase);
#pragma unroll
    for (int i = 0; i < 2; ++i)
      gl_lds16(Bw + bbase + (size_t)(i * 64) * ldb + k0,
               Bs + i * 4096 + dbase);
    __syncthreads();
    __builtin_amdgcn_s_setprio(1);
#pragma unroll
    for (int kk = 0; kk < 64; kk += 32) {
      bf16x8 af[4], bf[4];
#pragma unroll
      for (int mi = 0; mi < 4; ++mi) {
        int row = wr * 64 + mi * 16 + lrow;
        af[mi] = *(const bf16x8*)(&As[row * 64 + ((kk + g8) ^ rx)]);
      }
#pragma unroll
      for (int ni = 0; ni < 4; ++ni) {
        int row = wc * 64 + ni * 16 + lrow;
        bf[ni] = *(const bf16x8*)(&Bs[row * 64 + ((kk + g8) ^ rx)]);
      }
#pragma unroll
      for (int mi = 0; mi < 4; ++mi)
#pragma unroll
        for (int ni = 0; ni < 4; ++ni)
          acc[mi][ni] = __builtin_amdgcn_mfma_f32_16x16x32_bf16(
              af[mi], bf[ni], acc[mi][ni], 0, 0, 0);
    }
    __builtin_amdgcn_s_setprio(0);
    __syncthreads();
  }

  const int erow = (lane >> 4) * 4;
  const int ecol = lane & 15;
#pragma unroll
  for (int mi = 0; mi < 4; ++mi) {
#pragma unroll
    for (int ni = 0; ni < 4; ++ni) {
      int gcol = n0 + wc * 64 + ni * 16 + ecol;
      float bv = bias[gcol];
#pragma unroll
      for (int r4 = 0; r4 < 4; ++r4) {
        int grow = m0 + wr * 64 + mi * 16 + erow + r4;
        float v = acc[mi][ni][r4] + bv;
        if (EPI == EPI_QKV) {
          float vv = (gcol < 384) ? v * 0.17677669529663689f : v;
          obf[(size_t)grow * ldc + gcol] = f2bf(vv);
        } else if (EPI == EPI_GELU) {
          obf[(size_t)grow * ldc + gcol] = f2bf(gelu_fast(v));
        } else if (EPI == EPI_PROJ) {
          int nwin = grow / 49, l = grow % 49;
          int bb = nwin >> 6, wi = nwin & 63;
          int wh = wi >> 3, ww = wi & 7;
          int rr = l / 7, cc = l % 7;
          int sr = wh * 7 + rr + 3; if (sr >= 56) sr -= 56;
          int sc = ww * 7 + cc + 3; if (sc >= 56) sc -= 56;
          size_t idx = ((size_t)(bb * 3136 + sr * 56 + sc)) * 384 + gcol;
          obf[idx] = f2bf(addsrc[idx] + v);  // x -> bf16
        } else {  // EPI_FC2: out = x(bf16) + mlp, single fp32 write
          size_t idx = (size_t)grow * 384 + gcol;
          of32[idx] = bf2f(xres[idx]) + v;
        }
      }
    }
  }
}

// ---------------- MFMA windowed attention v5: 4 heads / 256-thr block -----
// Per-wave body identical to v4 (verified); waves are independent.
__global__ __launch_bounds__(256) void k_attn2(const u16* __restrict__ qkv,
                                               const float* __restrict__ tbl,
                                               u16* __restrict__ out) {
  __shared__ u16 P[4][64 * 64];  // 8KB per wave
  const int wid = threadIdx.x >> 6;
  const int id = blockIdx.x * 4 + wid;
  const int n = id / 12, h = id - n * 12;
  const int lane = threadIdx.x & 63;
  const int g = lane >> 4, c = lane & 15;
  u16* Pw = P[wid];
  const u16* base = qkv + (size_t)n * 56448 + h * 32;
  const int wi = n & 63;
  const int wt = (((wi >> 3) == 7) ? 2 : 0) | (((wi & 7) == 7) ? 1 : 0);
  const float* T = tbl + (size_t)((h << 2) | wt) * 4096;

  f32x4 st[4][4];  // [kj][qi]; reg r -> j = kj*16+g*4+r, i = qi*16+c
#pragma unroll
  for (int kj = 0; kj < 4; ++kj)
#pragma unroll
    for (int r = 0; r < 4; ++r) {
      f32x4 v4 = *(const f32x4*)(T + ((((kj * 4 + r) * 4 + g) * 16 + c) << 2));
#pragma unroll
      for (int qi = 0; qi < 4; ++qi) st[kj][qi][r] = v4[qi];
    }

  bf16x8 qf[4], kf[4];
#pragma unroll
  for (int t = 0; t < 4; ++t) {
    int row = t * 16 + c; if (row > 48) row = 48;
    qf[t] = *(const bf16x8*)(base + (size_t)row * 1152 + g * 8);
    kf[t] = *(const bf16x8*)(base + (size_t)row * 1152 + 384 + g * 8);
  }

  __builtin_amdgcn_s_setprio(1);
#pragma unroll
  for (int kj = 0; kj < 4; ++kj)
#pragma unroll
    for (int qi = 0; qi < 4; ++qi)
      st[kj][qi] = __builtin_amdgcn_mfma_f32_16x16x32_bf16(kf[kj], qf[qi],
                                                           st[kj][qi], 0, 0, 0);
  __builtin_amdgcn_s_setprio(0);

#pragma unroll
  for (int qi = 0; qi < 4; ++qi) {
    float m = -3e38f;
#pragma unroll
    for (int kj = 0; kj < 4; ++kj)
#pragma unroll
      for (int r = 0; r < 4; ++r) m = fmaxf(m, st[kj][qi][r]);
    m = fmaxf(m, __shfl_xor(m, 16));
    m = fmaxf(m, __shfl_xor(m, 32));
    float sum = 0.f;
#pragma unroll
    for (int kj = 0; kj < 4; ++kj)
#pragma unroll
      for (int r = 0; r < 4; ++r) {
        float e = __expf(st[kj][qi][r] - m);
        st[kj][qi][r] = e;
        sum += e;
      }
    sum += __shfl_xor(sum, 16);
    sum += __shfl_xor(sum, 32);
    float inv = 1.f / sum;
    int i = qi * 16 + c;
#pragma unroll
    for (int kj = 0; kj < 4; ++kj)
#pragma unroll
      for (int hh = 0; hh < 2; ++hh) {
        u32 pk = (u32)f2bf(st[kj][qi][2 * hh] * inv) |
                 ((u32)f2bf(st[kj][qi][2 * hh + 1] * inv) << 16);
        int idx = (i * 64 + kj * 16 + g * 4 + 2 * hh) ^ ((i & 7) << 3);
        *(u32*)(Pw + idx) = pk;
      }
  }

  f32x4 o[4][2] = {};
#pragma unroll
  for (int k0 = 0; k0 < 2; ++k0) {
    bf16x8 pa[4], vb[2];
#pragma unroll
    for (int qi = 0; qi < 4; ++qi) {
      int qq = qi * 16 + c;
      pa[qi] =
          *(const bf16x8*)(Pw + ((qq * 64 + k0 * 32 + g * 8) ^ ((qq & 7) << 3)));
    }
#pragma unroll
    for (int ni = 0; ni < 2; ++ni) {
      union { bf16x8 v; u16 a[8]; } vu;
#pragma unroll
      for (int e = 0; e < 8; ++e) {
        int j = k0 * 32 + g * 8 + e;
        int jr = j > 48 ? 48 : j;
        vu.a[e] = base[(size_t)jr * 1152 + 768 + ni * 16 + c];
      }
      vb[ni] = vu.v;
    }
    __builtin_amdgcn_s_setprio(1);
#pragma unroll
    for (int ni = 0; ni < 2; ++ni)
#pragma unroll
      for (int qi = 0; qi < 4; ++qi)
        o[qi][ni] = __builtin_amdgcn_mfma_f32_16x16x32_bf16(pa[qi], vb[ni],
                                                            o[qi][ni], 0, 0, 0);
    __builtin_amdgcn_s_setprio(0);
  }

  u16* ob = out + (size_t)n * 18816 + h * 32;
#pragma unroll
  for (int qi = 0; qi < 4; ++qi)
#pragma unroll
    for (int r = 0; r < 4; ++r) {
      int qq = qi * 16 + g * 4 + r;
      if (qq < 49) {
#pragma unroll
        for (int ni = 0; ni < 2; ++ni)
          ob[(size_t)qq * 384 + ni * 16 + c] = f2bf(o[qi][ni][r]);
      }
    }
}

// --------------------------------------------------------------------------
extern "C" void kernel_launch(void* const* d_in, const int* in_sizes, int n_in,
                              void* d_out, int out_size, void* d_ws,
                              size_t ws_size, hipStream_t stream) {
  const float* hidden = (const float*)d_in[0];
  const float* ln1g = (const float*)d_in[1];
  const float* ln1b = (const float*)d_in[2];
  const float* qkvw = (const float*)d_in[3];
  const float* qkvb = (const float*)d_in[4];
  const float* outw = (const float*)d_in[5];
  const float* outb = (const float*)d_in[6];
  const float* relt = (const float*)d_in[7];
  const float* ln2g = (const float*)d_in[8];
  const float* ln2b = (const float*)d_in[9];
  const float* fc1w = (const float*)d_in[10];
  const float* fc1b = (const float*)d_in[11];
  const float* fc2w = (const float*)d_in[12];
  const float* fc2b = (const float*)d_in[13];
  float* out = (float*)d_out;

  // ws layout (u16 units), peak 312 MB:
  u16* wq = (u16*)d_ws;            // 1152*384 (dead after qkv GEMM -> tbl)
  u16* wo = wq + 442368;           // 384*384
  u16* w1 = wo + 147456;           // 1536*384
  u16* w2 = w1 + 589824;           // 384*1536
  u16* xw = w2 + 589824;           // 100352*384: LN1 out / attn_out, then xn
  u16* qkv = xw + 38535168;        // 100352*1152 (dead after attn)
  u16* xbuf = qkv;                 // 100352*384 bf16 x (proj out, fc2 res)
  u16* hbuf = qkv + 38535168;      // 50176*1536 (row-half MLP buffer)
  u16* xn = xw;                    // LN2 out reuses xw (dead after proj)
  float* tbl = (float*)wq;         // 196608 f32 <= wq region (221184 f32)

  k_f2bf4<<<6912, 256, 0, stream>>>(qkvw, outw, fc1w, fc2w, wq, wo, w1, w2);

  // LN1 + shift + window partition
  k_ln<1><<<25088, 256, 0, stream>>>(hidden, ln1g, ln1b, xw);

  // qkv = xw @ qkv_w^T + b  (q cols pre-scaled by 1/sqrt(32))
  k_gemm3<EPI_QKV><<<392 * 9, 512, 0, stream>>>(
      xw, wq, qkvb, qkv, nullptr, nullptr, nullptr, 384, 384, 384, 1152, 9);

  // bias+mask tables (lane-major) into the now-dead wq region
  k_tbl<<<768, 256, 0, stream>>>(relt, tbl);

  // MFMA attention, 4 heads/block (writes attn_out into xw buffer)
  k_attn2<<<6144, 256, 0, stream>>>(qkv, tbl, xw);

  // out proj + window reverse + unshift + residual -> bf16 xbuf
  k_gemm3<EPI_PROJ><<<392 * 3, 512, 0, stream>>>(
      xw, wo, outb, xbuf, nullptr, hidden, nullptr, 384, 384, 384, 384, 3);

  // LN2 (bf16 in) -> xn (in xw region; xw is dead after proj)
  k_ln_bf<<<25088, 256, 0, stream>>>(xbuf, ln2g, ln2b, xn);

  // MLP, M-chunked (two row-halves); fc2 writes d_out = x + mlp (fp32)
  for (int ch = 0; ch < 2; ++ch) {
    const u16* xa = xn + (size_t)ch * 50176 * 384;
    const u16* xr = xbuf + (size_t)ch * 50176 * 384;
    float* oc = out + (size_t)ch * 50176 * 384;
    k_gemm3<EPI_GELU><<<196 * 12, 512, 0, stream>>>(
        xa, w1, fc1b, hbuf, nullptr, nullptr, nullptr, 384, 384, 384, 1536, 12);
    k_gemm3<EPI_FC2><<<196 * 3, 512, 0, stream>>>(
        hbuf, w2, fc2b, nullptr, oc, nullptr, xr, 1536, 1536, 1536, 384, 3);
  }
}